// Round 1
// baseline (8969.199 us; speedup 1.0000x reference)
//
#include <hip/hip_runtime.h>

#define FDIM 128
#define LN_EPS 1e-5f

// ---------------- degree / norm precompute ----------------

__global__ void k_init_deg(float* __restrict__ deg, int N) {
    int i = blockIdx.x * blockDim.x + threadIdx.x;
    if (i < N) deg[i] = 1.0f;  // self-loop
}

__global__ void k_count_deg(const int* __restrict__ dst, float* __restrict__ deg, int E) {
    int e = blockIdx.x * blockDim.x + threadIdx.x;
    if (e < E) atomicAdd(&deg[dst[e]], 1.0f);
}

__global__ void k_dinv(const float* __restrict__ deg, float* __restrict__ dinv, int N) {
    int i = blockIdx.x * blockDim.x + threadIdx.x;
    if (i < N) dinv[i] = rsqrtf(deg[i]);
}

__global__ void k_norm(const int* __restrict__ src, const int* __restrict__ dst,
                       const float* __restrict__ dinv, float* __restrict__ norm, int E) {
    int e = blockIdx.x * blockDim.x + threadIdx.x;
    if (e < E) norm[e] = dinv[src[e]] * dinv[dst[e]];
}

// ---------------- GEMM: C[N,128] = X[N,128] @ W[128,128] ----------------
// Block: 256 threads, tile = 32 rows x 128 cols, 4x4 register tile per thread.

__launch_bounds__(256)
__global__ void k_gemm(const float* __restrict__ X, const float* __restrict__ W,
                       float* __restrict__ C) {
    __shared__ float xs[32 * FDIM];
    const int t = threadIdx.x;
    const size_t row0 = (size_t)blockIdx.x * 32;

    // stage 32 contiguous rows (32*128 floats = 1024 float4)
    const float4* gx = (const float4*)(X + row0 * FDIM);
    float4* sx = (float4*)xs;
#pragma unroll
    for (int i = 0; i < 4; i++) sx[t + i * 256] = gx[t + i * 256];
    __syncthreads();

    const int cg = t & 31;   // col group: cols 4*cg .. 4*cg+3
    const int rg = t >> 5;   // row group: rows 4*rg .. 4*rg+3
    const int c0 = cg * 4;
    const int r0 = rg * 4;

    float4 a0 = {0, 0, 0, 0}, a1 = {0, 0, 0, 0}, a2 = {0, 0, 0, 0}, a3 = {0, 0, 0, 0};
    const float* wp = W + c0;
#pragma unroll 4
    for (int k = 0; k < FDIM; k++) {
        const float4 wv = *(const float4*)(wp + k * FDIM);
        const float x0 = xs[(r0 + 0) * FDIM + k];
        const float x1 = xs[(r0 + 1) * FDIM + k];
        const float x2 = xs[(r0 + 2) * FDIM + k];
        const float x3 = xs[(r0 + 3) * FDIM + k];
        a0.x += x0 * wv.x; a0.y += x0 * wv.y; a0.z += x0 * wv.z; a0.w += x0 * wv.w;
        a1.x += x1 * wv.x; a1.y += x1 * wv.y; a1.z += x1 * wv.z; a1.w += x1 * wv.w;
        a2.x += x2 * wv.x; a2.y += x2 * wv.y; a2.z += x2 * wv.z; a2.w += x2 * wv.w;
        a3.x += x3 * wv.x; a3.y += x3 * wv.y; a3.z += x3 * wv.z; a3.w += x3 * wv.w;
    }
    float* cp = C + (row0 + r0) * FDIM + c0;
    *(float4*)(cp + 0 * FDIM) = a0;
    *(float4*)(cp + 1 * FDIM) = a1;
    *(float4*)(cp + 2 * FDIM) = a2;
    *(float4*)(cp + 3 * FDIM) = a3;
}

// ---------------- message passing ----------------

// agg[n] = dinv[n]^2 * xw[n]   (self-loop term; fully initializes agg)
__global__ void k_selfloop(const float* __restrict__ xw, const float* __restrict__ dinv,
                           float* __restrict__ agg, int N) {
    int tid = blockIdx.x * blockDim.x + threadIdx.x;
    int n = tid >> 5;
    if (n >= N) return;
    int f4 = tid & 31;
    float c = dinv[n];
    c *= c;
    float4 v = ((const float4*)xw)[(size_t)n * 32 + f4];
    v.x *= c; v.y *= c; v.z *= c; v.w *= c;
    ((float4*)agg)[(size_t)n * 32 + f4] = v;
}

// agg[dst[e]] += norm[e] * xw[src[e]]  (32 threads per edge, 4 floats each)
__global__ void k_edge_scatter(const float* __restrict__ xw, float* __restrict__ agg,
                               const int* __restrict__ src, const int* __restrict__ dst,
                               const float* __restrict__ norm, int E) {
    int tid = blockIdx.x * blockDim.x + threadIdx.x;
    int e = tid >> 5;
    if (e >= E) return;
    int f = (tid & 31) << 2;
    int s = src[e];
    int d = dst[e];
    float c = norm[e];
    const float4 v = *(const float4*)(xw + (size_t)s * FDIM + f);
    float* out = agg + (size_t)d * FDIM + f;
    atomicAdd(out + 0, c * v.x);
    atomicAdd(out + 1, c * v.y);
    atomicAdd(out + 2, c * v.z);
    atomicAdd(out + 3, c * v.w);
}

// x = agg + b, optional relu (in-place on agg)
__global__ void k_bias_act(float* __restrict__ agg, const float* __restrict__ b,
                           int N, int do_relu) {
    int tid = blockIdx.x * blockDim.x + threadIdx.x;
    int n = tid >> 5;
    if (n >= N) return;
    int f = (tid & 31) << 2;
    float4 v = ((float4*)agg)[(size_t)n * 32 + (tid & 31)];
    const float4 bb = *(const float4*)(b + f);
    v.x += bb.x; v.y += bb.y; v.z += bb.z; v.w += bb.w;
    if (do_relu) {
        v.x = fmaxf(v.x, 0.f); v.y = fmaxf(v.y, 0.f);
        v.z = fmaxf(v.z, 0.f); v.w = fmaxf(v.w, 0.f);
    }
    ((float4*)agg)[(size_t)n * 32 + (tid & 31)] = v;
}

// ---------------- pool + MLP + LayerNorm (64 blocks x 128 threads) ----------------

__launch_bounds__(128)
__global__ void k_final(const float* __restrict__ x3, const int* __restrict__ batch, int N,
                        const float* __restrict__ Wm1, const float* __restrict__ bm1,
                        const float* __restrict__ Wm2, const float* __restrict__ bm2,
                        const float* __restrict__ ln_g, const float* __restrict__ ln_b,
                        float* __restrict__ out) {
    const int g = blockIdx.x;
    const int t = threadIdx.x;

    // lower_bound(batch, g) and lower_bound(batch, g+1) — batch is sorted
    int lo = 0, hi = N;
    while (lo < hi) { int mid = (lo + hi) >> 1; if (batch[mid] < g) lo = mid + 1; else hi = mid; }
    int lo2 = lo, hi2 = N;
    while (lo2 < hi2) { int mid = (lo2 + hi2) >> 1; if (batch[mid] < g + 1) lo2 = mid + 1; else hi2 = mid; }

    float acc = 0.f;
    for (int n = lo; n < lo2; n++) acc += x3[(size_t)n * FDIM + t];
    float cnt = (float)(lo2 - lo);
    float gl = acc / fmaxf(cnt, 1.0f);

    __shared__ float gbuf[FDIM];
    __shared__ float hbuf[FDIM];
    __shared__ float wsum[4];
    gbuf[t] = gl;
    __syncthreads();

    float h = bm1[t];
#pragma unroll 8
    for (int k = 0; k < FDIM; k++) h += gbuf[k] * Wm1[k * FDIM + t];
    h = fmaxf(h, 0.f);
    hbuf[t] = h;
    __syncthreads();

    float y = bm2[t];
#pragma unroll 8
    for (int k = 0; k < FDIM; k++) y += hbuf[k] * Wm2[k * FDIM + t];

    // LayerNorm over 128 cols (2 waves)
    float s = y, s2 = y * y;
#pragma unroll
    for (int off = 32; off > 0; off >>= 1) {
        s += __shfl_down(s, off, 64);
        s2 += __shfl_down(s2, off, 64);
    }
    if ((t & 63) == 0) { wsum[t >> 6] = s; wsum[2 + (t >> 6)] = s2; }
    __syncthreads();
    float sum = wsum[0] + wsum[1];
    float sumsq = wsum[2] + wsum[3];
    float mu = sum * (1.0f / FDIM);
    float var = sumsq * (1.0f / FDIM) - mu * mu;
    float r = rsqrtf(var + LN_EPS);
    out[g * FDIM + t] = (y - mu) * r * ln_g[t] + ln_b[t];
}

// ---------------- launch ----------------

extern "C" void kernel_launch(void* const* d_in, const int* in_sizes, int n_in,
                              void* d_out, int out_size, void* d_ws, size_t ws_size,
                              hipStream_t stream) {
    const float* x_in  = (const float*)d_in[0];
    const int*   eidx  = (const int*)d_in[1];
    const int*   batch = (const int*)d_in[2];
    const float* W1 = (const float*)d_in[3];
    const float* b1 = (const float*)d_in[4];
    const float* W2 = (const float*)d_in[5];
    const float* b2 = (const float*)d_in[6];
    const float* W3 = (const float*)d_in[7];
    const float* b3 = (const float*)d_in[8];
    const float* Wm1 = (const float*)d_in[9];
    const float* bm1 = (const float*)d_in[10];
    const float* Wm2 = (const float*)d_in[11];
    const float* bm2 = (const float*)d_in[12];
    const float* ln_g = (const float*)d_in[13];
    const float* ln_b = (const float*)d_in[14];
    float* out = (float*)d_out;

    const int N = in_sizes[0] / FDIM;   // 100000
    const int E = in_sizes[1] / 2;      // 1600000
    const int G = out_size / FDIM;      // 64

    const int* src = eidx;
    const int* dst = eidx + E;

    float* ws = (float*)d_ws;
    float* deg  = ws;
    float* dinv = deg + N;
    float* norm = dinv + N;
    float* B0 = norm + E;                      // xw scratch
    float* B1 = B0 + (size_t)N * FDIM;         // agg / x1 / x3
    float* B2 = B1 + (size_t)N * FDIM;         // agg / x2

    const int TPB = 256;
    dim3 blk(TPB);
    dim3 gN((N + TPB - 1) / TPB);
    dim3 gE((E + TPB - 1) / TPB);
    dim3 gN32(((size_t)N * 32 + TPB - 1) / TPB);
    dim3 gE32(((size_t)E * 32 + TPB - 1) / TPB);
    dim3 gGemm(N / 32);

    // degree + norm
    k_init_deg<<<gN, blk, 0, stream>>>(deg, N);
    k_count_deg<<<gE, blk, 0, stream>>>(dst, deg, E);
    k_dinv<<<gN, blk, 0, stream>>>(deg, dinv, N);
    k_norm<<<gE, blk, 0, stream>>>(src, dst, dinv, norm, E);

    // layer 1: x_in -> B1
    k_gemm<<<gGemm, blk, 0, stream>>>(x_in, W1, B0);
    k_selfloop<<<gN32, blk, 0, stream>>>(B0, dinv, B1, N);
    k_edge_scatter<<<gE32, blk, 0, stream>>>(B0, B1, src, dst, norm, E);
    k_bias_act<<<gN32, blk, 0, stream>>>(B1, b1, N, 1);

    // layer 2: B1 -> B2
    k_gemm<<<gGemm, blk, 0, stream>>>(B1, W2, B0);
    k_selfloop<<<gN32, blk, 0, stream>>>(B0, dinv, B2, N);
    k_edge_scatter<<<gE32, blk, 0, stream>>>(B0, B2, src, dst, norm, E);
    k_bias_act<<<gN32, blk, 0, stream>>>(B2, b2, N, 1);

    // layer 3: B2 -> B1 (no relu)
    k_gemm<<<gGemm, blk, 0, stream>>>(B2, W3, B0);
    k_selfloop<<<gN32, blk, 0, stream>>>(B0, dinv, B1, N);
    k_edge_scatter<<<gE32, blk, 0, stream>>>(B0, B1, src, dst, norm, E);
    k_bias_act<<<gN32, blk, 0, stream>>>(B1, b3, N, 0);

    // pool + MLP + LN
    k_final<<<dim3(G), dim3(FDIM), 0, stream>>>(B1, batch, N, Wm1, bm1, Wm2, bm2,
                                                ln_g, ln_b, out);
}

// Round 2
// 1248.279 us; speedup vs baseline: 7.1852x; 7.1852x over previous
//
#include <hip/hip_runtime.h>

#define FDIM 128
#define LN_EPS 1e-5f
#define SCAN_TPB 256

// ---------------- degree / norm precompute ----------------

__global__ void k_count(const int* __restrict__ dst, int* __restrict__ indeg, int E) {
    int e = blockIdx.x * blockDim.x + threadIdx.x;
    if (e < E) atomicAdd(&indeg[dst[e]], 1);
}

__global__ void k_dinv(const int* __restrict__ indeg, float* __restrict__ dinv, int N) {
    int i = blockIdx.x * blockDim.x + threadIdx.x;
    if (i < N) dinv[i] = rsqrtf((float)(indeg[i] + 1));  // +1 self-loop
}

// ---------------- prefix scan (3-kernel, exact CSR offsets) ----------------

__global__ void k_scan_chunk(const int* __restrict__ in, int* __restrict__ row_ptr,
                             int* __restrict__ partials, int N) {
    __shared__ int wsum[16];
    const int t = threadIdx.x;
    const int i = blockIdx.x * SCAN_TPB + t;
    int v = (i < N) ? in[i] : 0;
    const int lane = t & 63;
    const int wv = t >> 6;
    int x = v;
#pragma unroll
    for (int off = 1; off < 64; off <<= 1) {
        int y = __shfl_up(x, off, 64);
        if (lane >= off) x += y;
    }
    if (lane == 63) wsum[wv] = x;
    __syncthreads();
    if (t == 0) {
        int s = 0;
        for (int w = 0; w < SCAN_TPB / 64; w++) { int tmp = wsum[w]; wsum[w] = s; s += tmp; }
        partials[blockIdx.x] = s;
    }
    __syncthreads();
    x += wsum[wv];
    if (i < N) row_ptr[i + 1] = x;  // inclusive scan -> row_ptr shifted by 1
    if (i == 0) row_ptr[0] = 0;
}

// single block, 1024 threads; NB <= 1024
__global__ void k_scan_partials(int* __restrict__ partials, int NB) {
    __shared__ int wsum[16];
    const int t = threadIdx.x;
    int v = (t < NB) ? partials[t] : 0;
    const int lane = t & 63;
    const int wv = t >> 6;
    int x = v;
#pragma unroll
    for (int off = 1; off < 64; off <<= 1) {
        int y = __shfl_up(x, off, 64);
        if (lane >= off) x += y;
    }
    if (lane == 63) wsum[wv] = x;
    __syncthreads();
    if (t == 0) {
        int s = 0;
        for (int w = 0; w < 16; w++) { int tmp = wsum[w]; wsum[w] = s; s += tmp; }
    }
    __syncthreads();
    x += wsum[wv];
    if (t < NB) partials[t] = x - v;  // exclusive
}

__global__ void k_scan_add(int* __restrict__ row_ptr, const int* __restrict__ partials, int N) {
    int i = blockIdx.x * SCAN_TPB + threadIdx.x;
    if (i < N) row_ptr[i + 1] += partials[blockIdx.x];
}

// ---------------- CSR fill ----------------

__global__ void k_fill_csr(const int* __restrict__ src, const int* __restrict__ dst,
                           const float* __restrict__ dinv, const int* __restrict__ row_ptr,
                           int* __restrict__ cursor, int* __restrict__ csr_src,
                           float* __restrict__ csr_w, int E) {
    int e = blockIdx.x * blockDim.x + threadIdx.x;
    if (e >= E) return;
    int s = src[e], d = dst[e];
    int pos = atomicAdd(&cursor[d], 1);
    int slot = row_ptr[d] + pos;
    csr_src[slot] = s;
    csr_w[slot] = dinv[s] * dinv[d];
}

// ---------------- GEMM: C[N,128] = X[N,128] @ W[128,128] ----------------

__launch_bounds__(256)
__global__ void k_gemm(const float* __restrict__ X, const float* __restrict__ W,
                       float* __restrict__ C) {
    __shared__ float xs[32 * FDIM];
    const int t = threadIdx.x;
    const size_t row0 = (size_t)blockIdx.x * 32;

    const float4* gx = (const float4*)(X + row0 * FDIM);
    float4* sx = (float4*)xs;
#pragma unroll
    for (int i = 0; i < 4; i++) sx[t + i * 256] = gx[t + i * 256];
    __syncthreads();

    const int cg = t & 31;
    const int rg = t >> 5;
    const int c0 = cg * 4;
    const int r0 = rg * 4;

    float4 a0 = {0, 0, 0, 0}, a1 = {0, 0, 0, 0}, a2 = {0, 0, 0, 0}, a3 = {0, 0, 0, 0};
    const float* wp = W + c0;
#pragma unroll 4
    for (int k = 0; k < FDIM; k++) {
        const float4 wv = *(const float4*)(wp + k * FDIM);
        const float x0 = xs[(r0 + 0) * FDIM + k];
        const float x1 = xs[(r0 + 1) * FDIM + k];
        const float x2 = xs[(r0 + 2) * FDIM + k];
        const float x3 = xs[(r0 + 3) * FDIM + k];
        a0.x += x0 * wv.x; a0.y += x0 * wv.y; a0.z += x0 * wv.z; a0.w += x0 * wv.w;
        a1.x += x1 * wv.x; a1.y += x1 * wv.y; a1.z += x1 * wv.z; a1.w += x1 * wv.w;
        a2.x += x2 * wv.x; a2.y += x2 * wv.y; a2.z += x2 * wv.z; a2.w += x2 * wv.w;
        a3.x += x3 * wv.x; a3.y += x3 * wv.y; a3.z += x3 * wv.z; a3.w += x3 * wv.w;
    }
    float* cp = C + (row0 + r0) * FDIM + c0;
    *(float4*)(cp + 0 * FDIM) = a0;
    *(float4*)(cp + 1 * FDIM) = a1;
    *(float4*)(cp + 2 * FDIM) = a2;
    *(float4*)(cp + 3 * FDIM) = a3;
}

// ---------------- fused pull-aggregate: selfloop + gather + bias + relu ----------------
// 32 threads per node, float4 per thread. out[n] = act(dinv[n]^2*xw[n] + sum_e w_e*xw[src_e] + b)

__launch_bounds__(256)
__global__ void k_aggregate(const float* __restrict__ xw, const int* __restrict__ row_ptr,
                            const int* __restrict__ csr_src, const float* __restrict__ csr_w,
                            const float* __restrict__ dinv, const float* __restrict__ bias,
                            float* __restrict__ out, int N, int do_relu) {
    int tid = blockIdx.x * blockDim.x + threadIdx.x;
    int n = tid >> 5;
    if (n >= N) return;
    int lane = tid & 31;

    float d = dinv[n];
    float c = d * d;
    float4 acc = ((const float4*)xw)[(size_t)n * 32 + lane];
    acc.x *= c; acc.y *= c; acc.z *= c; acc.w *= c;

    const int beg = row_ptr[n];
    const int end = row_ptr[n + 1];
    for (int e = beg; e < end; e++) {
        int s = csr_src[e];
        float w = csr_w[e];
        float4 v = ((const float4*)xw)[(size_t)s * 32 + lane];
        acc.x += w * v.x; acc.y += w * v.y; acc.z += w * v.z; acc.w += w * v.w;
    }

    const float4 bb = ((const float4*)bias)[lane];
    acc.x += bb.x; acc.y += bb.y; acc.z += bb.z; acc.w += bb.w;
    if (do_relu) {
        acc.x = fmaxf(acc.x, 0.f); acc.y = fmaxf(acc.y, 0.f);
        acc.z = fmaxf(acc.z, 0.f); acc.w = fmaxf(acc.w, 0.f);
    }
    ((float4*)out)[(size_t)n * 32 + lane] = acc;
}

// ---------------- pool + MLP + LayerNorm (64 blocks x 128 threads) ----------------

__launch_bounds__(128)
__global__ void k_final(const float* __restrict__ x3, const int* __restrict__ batch, int N,
                        const float* __restrict__ Wm1, const float* __restrict__ bm1,
                        const float* __restrict__ Wm2, const float* __restrict__ bm2,
                        const float* __restrict__ ln_g, const float* __restrict__ ln_b,
                        float* __restrict__ out) {
    const int g = blockIdx.x;
    const int t = threadIdx.x;

    int lo = 0, hi = N;
    while (lo < hi) { int mid = (lo + hi) >> 1; if (batch[mid] < g) lo = mid + 1; else hi = mid; }
    int lo2 = lo, hi2 = N;
    while (lo2 < hi2) { int mid = (lo2 + hi2) >> 1; if (batch[mid] < g + 1) lo2 = mid + 1; else hi2 = mid; }

    float acc = 0.f;
    for (int n = lo; n < lo2; n++) acc += x3[(size_t)n * FDIM + t];
    float cnt = (float)(lo2 - lo);
    float gl = acc / fmaxf(cnt, 1.0f);

    __shared__ float gbuf[FDIM];
    __shared__ float hbuf[FDIM];
    __shared__ float wsum[4];
    gbuf[t] = gl;
    __syncthreads();

    float h = bm1[t];
#pragma unroll 8
    for (int k = 0; k < FDIM; k++) h += gbuf[k] * Wm1[k * FDIM + t];
    h = fmaxf(h, 0.f);
    hbuf[t] = h;
    __syncthreads();

    float y = bm2[t];
#pragma unroll 8
    for (int k = 0; k < FDIM; k++) y += hbuf[k] * Wm2[k * FDIM + t];

    float s = y, s2 = y * y;
#pragma unroll
    for (int off = 32; off > 0; off >>= 1) {
        s += __shfl_down(s, off, 64);
        s2 += __shfl_down(s2, off, 64);
    }
    if ((t & 63) == 0) { wsum[t >> 6] = s; wsum[2 + (t >> 6)] = s2; }
    __syncthreads();
    float sum = wsum[0] + wsum[1];
    float sumsq = wsum[2] + wsum[3];
    float mu = sum * (1.0f / FDIM);
    float var = sumsq * (1.0f / FDIM) - mu * mu;
    float r = rsqrtf(var + LN_EPS);
    out[g * FDIM + t] = (y - mu) * r * ln_g[t] + ln_b[t];
}

// ---------------- launch ----------------

extern "C" void kernel_launch(void* const* d_in, const int* in_sizes, int n_in,
                              void* d_out, int out_size, void* d_ws, size_t ws_size,
                              hipStream_t stream) {
    const float* x_in  = (const float*)d_in[0];
    const int*   eidx  = (const int*)d_in[1];
    const int*   batch = (const int*)d_in[2];
    const float* W1 = (const float*)d_in[3];
    const float* b1 = (const float*)d_in[4];
    const float* W2 = (const float*)d_in[5];
    const float* b2 = (const float*)d_in[6];
    const float* W3 = (const float*)d_in[7];
    const float* b3 = (const float*)d_in[8];
    const float* Wm1 = (const float*)d_in[9];
    const float* bm1 = (const float*)d_in[10];
    const float* Wm2 = (const float*)d_in[11];
    const float* bm2 = (const float*)d_in[12];
    const float* ln_g = (const float*)d_in[13];
    const float* ln_b = (const float*)d_in[14];
    float* out = (float*)d_out;

    const int N = in_sizes[0] / FDIM;   // 100000
    const int E = in_sizes[1] / 2;      // 1600000
    const int G = out_size / FDIM;      // 64

    const int* src = eidx;
    const int* dst = eidx + E;

    // workspace layout (16B-aligned chunks)
    char* p = (char*)d_ws;
    float* B0 = (float*)p;            p += (size_t)N * FDIM * 4;   // xw scratch
    float* B1 = (float*)p;            p += (size_t)N * FDIM * 4;   // layer output
    int* csr_src = (int*)p;           p += (size_t)E * 4;
    float* csr_w = (float*)p;         p += (size_t)E * 4;
    int* row_ptr = (int*)p;           p += (size_t)(N + 1) * 4;
    int* indeg = (int*)p;             p += (size_t)N * 4;
    int* cursor = (int*)p;            p += (size_t)N * 4;
    int* partials = (int*)p;          p += 1024 * 4;
    float* dinv = (float*)p;          p += (size_t)N * 4;

    const int TPB = 256;
    dim3 blk(TPB);
    dim3 gN((N + TPB - 1) / TPB);
    dim3 gE((E + TPB - 1) / TPB);
    dim3 gN32(((size_t)N * 32 + TPB - 1) / TPB);
    dim3 gGemm(N / 32);
    const int NB = (N + SCAN_TPB - 1) / SCAN_TPB;  // 391 <= 1024

    // ---- CSR build ----
    hipMemsetAsync(indeg, 0, (size_t)N * 4, stream);
    hipMemsetAsync(cursor, 0, (size_t)N * 4, stream);
    k_count<<<gE, blk, 0, stream>>>(dst, indeg, E);
    k_dinv<<<gN, blk, 0, stream>>>(indeg, dinv, N);
    k_scan_chunk<<<dim3(NB), dim3(SCAN_TPB), 0, stream>>>(indeg, row_ptr, partials, N);
    k_scan_partials<<<dim3(1), dim3(1024), 0, stream>>>(partials, NB);
    k_scan_add<<<dim3(NB), dim3(SCAN_TPB), 0, stream>>>(row_ptr, partials, N);
    k_fill_csr<<<gE, blk, 0, stream>>>(src, dst, dinv, row_ptr, cursor, csr_src, csr_w, E);

    // ---- layer 1: x_in -> B1 ----
    k_gemm<<<gGemm, blk, 0, stream>>>(x_in, W1, B0);
    k_aggregate<<<gN32, blk, 0, stream>>>(B0, row_ptr, csr_src, csr_w, dinv, b1, B1, N, 1);

    // ---- layer 2: B1 -> B1 (via B0) ----
    k_gemm<<<gGemm, blk, 0, stream>>>(B1, W2, B0);
    k_aggregate<<<gN32, blk, 0, stream>>>(B0, row_ptr, csr_src, csr_w, dinv, b2, B1, N, 1);

    // ---- layer 3: B1 -> B1 (via B0), no relu ----
    k_gemm<<<gGemm, blk, 0, stream>>>(B1, W3, B0);
    k_aggregate<<<gN32, blk, 0, stream>>>(B0, row_ptr, csr_src, csr_w, dinv, b3, B1, N, 0);

    // ---- pool + MLP + LN ----
    k_final<<<dim3(G), dim3(FDIM), 0, stream>>>(B1, batch, N, Wm1, bm1, Wm2, bm2,
                                                ln_g, ln_b, out);
}

// Round 3
// 916.255 us; speedup vs baseline: 9.7890x; 1.3624x over previous
//
#include <hip/hip_runtime.h>

#define FDIM 128
#define LN_EPS 1e-5f
#define SCAN_TPB 256

// ---------------- degree / norm precompute ----------------

__global__ void k_count(const int* __restrict__ dst, int* __restrict__ indeg, int E) {
    int e = blockIdx.x * blockDim.x + threadIdx.x;
    if (e < E) atomicAdd(&indeg[dst[e]], 1);
}

__global__ void k_dinv(const int* __restrict__ indeg, float* __restrict__ dinv, int N) {
    int i = blockIdx.x * blockDim.x + threadIdx.x;
    if (i < N) dinv[i] = rsqrtf((float)(indeg[i] + 1));  // +1 self-loop
}

// ---------------- prefix scan (3-kernel, exact CSR offsets) ----------------

__global__ void k_scan_chunk(const int* __restrict__ in, int* __restrict__ row_ptr,
                             int* __restrict__ partials, int N) {
    __shared__ int wsum[16];
    const int t = threadIdx.x;
    const int i = blockIdx.x * SCAN_TPB + t;
    int v = (i < N) ? in[i] : 0;
    const int lane = t & 63;
    const int wv = t >> 6;
    int x = v;
#pragma unroll
    for (int off = 1; off < 64; off <<= 1) {
        int y = __shfl_up(x, off, 64);
        if (lane >= off) x += y;
    }
    if (lane == 63) wsum[wv] = x;
    __syncthreads();
    if (t == 0) {
        int s = 0;
        for (int w = 0; w < SCAN_TPB / 64; w++) { int tmp = wsum[w]; wsum[w] = s; s += tmp; }
        partials[blockIdx.x] = s;
    }
    __syncthreads();
    x += wsum[wv];
    if (i < N) row_ptr[i + 1] = x;
    if (i == 0) row_ptr[0] = 0;
}

__global__ void k_scan_partials(int* __restrict__ partials, int NB) {
    __shared__ int wsum[16];
    const int t = threadIdx.x;
    int v = (t < NB) ? partials[t] : 0;
    const int lane = t & 63;
    const int wv = t >> 6;
    int x = v;
#pragma unroll
    for (int off = 1; off < 64; off <<= 1) {
        int y = __shfl_up(x, off, 64);
        if (lane >= off) x += y;
    }
    if (lane == 63) wsum[wv] = x;
    __syncthreads();
    if (t == 0) {
        int s = 0;
        for (int w = 0; w < 16; w++) { int tmp = wsum[w]; wsum[w] = s; s += tmp; }
    }
    __syncthreads();
    x += wsum[wv];
    if (t < NB) partials[t] = x - v;
}

__global__ void k_scan_add(int* __restrict__ row_ptr, const int* __restrict__ partials, int N) {
    int i = blockIdx.x * SCAN_TPB + threadIdx.x;
    if (i < N) row_ptr[i + 1] += partials[blockIdx.x];
}

// ---------------- CSR fill ----------------

__global__ void k_fill_csr(const int* __restrict__ src, const int* __restrict__ dst,
                           const float* __restrict__ dinv, const int* __restrict__ row_ptr,
                           int* __restrict__ cursor, int* __restrict__ csr_src,
                           float* __restrict__ csr_w, int E) {
    int e = blockIdx.x * blockDim.x + threadIdx.x;
    if (e >= E) return;
    int s = src[e], d = dst[e];
    int pos = atomicAdd(&cursor[d], 1);
    int slot = row_ptr[d] + pos;
    csr_src[slot] = s;
    csr_w[slot] = dinv[s] * dinv[d];
}

// ---------------- GEMM: C[N,128] = X[N,128] @ W[128,128] ----------------

__launch_bounds__(256)
__global__ void k_gemm(const float* __restrict__ X, const float* __restrict__ W,
                       float* __restrict__ C) {
    __shared__ float xs[32 * FDIM];
    const int t = threadIdx.x;
    const size_t row0 = (size_t)blockIdx.x * 32;

    const float4* gx = (const float4*)(X + row0 * FDIM);
    float4* sx = (float4*)xs;
#pragma unroll
    for (int i = 0; i < 4; i++) sx[t + i * 256] = gx[t + i * 256];
    __syncthreads();

    const int cg = t & 31;
    const int rg = t >> 5;
    const int c0 = cg * 4;
    const int r0 = rg * 4;

    float4 a0 = {0, 0, 0, 0}, a1 = {0, 0, 0, 0}, a2 = {0, 0, 0, 0}, a3 = {0, 0, 0, 0};
    const float* wp = W + c0;
#pragma unroll 4
    for (int k = 0; k < FDIM; k++) {
        const float4 wv = *(const float4*)(wp + k * FDIM);
        const float x0 = xs[(r0 + 0) * FDIM + k];
        const float x1 = xs[(r0 + 1) * FDIM + k];
        const float x2 = xs[(r0 + 2) * FDIM + k];
        const float x3 = xs[(r0 + 3) * FDIM + k];
        a0.x += x0 * wv.x; a0.y += x0 * wv.y; a0.z += x0 * wv.z; a0.w += x0 * wv.w;
        a1.x += x1 * wv.x; a1.y += x1 * wv.y; a1.z += x1 * wv.z; a1.w += x1 * wv.w;
        a2.x += x2 * wv.x; a2.y += x2 * wv.y; a2.z += x2 * wv.z; a2.w += x2 * wv.w;
        a3.x += x3 * wv.x; a3.y += x3 * wv.y; a3.z += x3 * wv.z; a3.w += x3 * wv.w;
    }
    float* cp = C + (row0 + r0) * FDIM + c0;
    *(float4*)(cp + 0 * FDIM) = a0;
    *(float4*)(cp + 1 * FDIM) = a1;
    *(float4*)(cp + 2 * FDIM) = a2;
    *(float4*)(cp + 3 * FDIM) = a3;
}

// ---------------- fused pull-aggregate: selfloop + gather + bias + relu ----------------

__launch_bounds__(256)
__global__ void k_aggregate(const float* __restrict__ xw, const int* __restrict__ row_ptr,
                            const int* __restrict__ csr_src, const float* __restrict__ csr_w,
                            const float* __restrict__ dinv, const float* __restrict__ bias,
                            float* __restrict__ out, int N, int do_relu) {
    int tid = blockIdx.x * blockDim.x + threadIdx.x;
    int n = tid >> 5;
    if (n >= N) return;
    int lane = tid & 31;

    float d = dinv[n];
    float c = d * d;
    float4 acc = ((const float4*)xw)[(size_t)n * 32 + lane];
    acc.x *= c; acc.y *= c; acc.z *= c; acc.w *= c;

    const int beg = row_ptr[n];
    const int end = row_ptr[n + 1];
    for (int e = beg; e < end; e++) {
        int s = csr_src[e];
        float w = csr_w[e];
        float4 v = ((const float4*)xw)[(size_t)s * 32 + lane];
        acc.x += w * v.x; acc.y += w * v.y; acc.z += w * v.z; acc.w += w * v.w;
    }

    const float4 bb = ((const float4*)bias)[lane];
    acc.x += bb.x; acc.y += bb.y; acc.z += bb.z; acc.w += bb.w;
    if (do_relu) {
        acc.x = fmaxf(acc.x, 0.f); acc.y = fmaxf(acc.y, 0.f);
        acc.z = fmaxf(acc.z, 0.f); acc.w = fmaxf(acc.w, 0.f);
    }
    ((float4*)out)[(size_t)n * 32 + lane] = acc;
}

// ---------------- two-stage pool ----------------
// stage 1: each block scans a contiguous 128-node slice; batch is sorted ->
// run-length accumulate, one atomicAdd per (run x feature).

#define POOL_NODES 128

__launch_bounds__(128)
__global__ void k_pool(const float* __restrict__ x3, const int* __restrict__ batch,
                       float* __restrict__ sums, int N) {
    const int t = threadIdx.x;
    const int n0 = blockIdx.x * POOL_NODES;
    if (n0 >= N) return;
    const int n1 = (n0 + POOL_NODES < N) ? n0 + POOL_NODES : N;

    float acc = 0.f;
    int cur = batch[n0];
    for (int n = n0; n < n1; n++) {
        int g = batch[n];
        if (g != cur) {
            atomicAdd(&sums[cur * FDIM + t], acc);
            acc = 0.f;
            cur = g;
        }
        acc += x3[(size_t)n * FDIM + t];
    }
    atomicAdd(&sums[cur * FDIM + t], acc);
}

// stage 2: per-graph mean + MLP + LayerNorm (G blocks x 128 threads)

__launch_bounds__(128)
__global__ void k_final(const float* __restrict__ sums, const int* __restrict__ batch, int N,
                        const float* __restrict__ Wm1, const float* __restrict__ bm1,
                        const float* __restrict__ Wm2, const float* __restrict__ bm2,
                        const float* __restrict__ ln_g, const float* __restrict__ ln_b,
                        float* __restrict__ out) {
    const int g = blockIdx.x;
    const int t = threadIdx.x;

    // count of nodes in graph g via binary search (batch sorted)
    int lo = 0, hi = N;
    while (lo < hi) { int mid = (lo + hi) >> 1; if (batch[mid] < g) lo = mid + 1; else hi = mid; }
    int lo2 = lo, hi2 = N;
    while (lo2 < hi2) { int mid = (lo2 + hi2) >> 1; if (batch[mid] < g + 1) lo2 = mid + 1; else hi2 = mid; }
    float cnt = (float)(lo2 - lo);

    float gl = sums[g * FDIM + t] / fmaxf(cnt, 1.0f);

    __shared__ float gbuf[FDIM];
    __shared__ float hbuf[FDIM];
    __shared__ float wsum[4];
    gbuf[t] = gl;
    __syncthreads();

    float h = bm1[t];
#pragma unroll 8
    for (int k = 0; k < FDIM; k++) h += gbuf[k] * Wm1[k * FDIM + t];
    h = fmaxf(h, 0.f);
    hbuf[t] = h;
    __syncthreads();

    float y = bm2[t];
#pragma unroll 8
    for (int k = 0; k < FDIM; k++) y += hbuf[k] * Wm2[k * FDIM + t];

    float s = y, s2 = y * y;
#pragma unroll
    for (int off = 32; off > 0; off >>= 1) {
        s += __shfl_down(s, off, 64);
        s2 += __shfl_down(s2, off, 64);
    }
    if ((t & 63) == 0) { wsum[t >> 6] = s; wsum[2 + (t >> 6)] = s2; }
    __syncthreads();
    float sum = wsum[0] + wsum[1];
    float sumsq = wsum[2] + wsum[3];
    float mu = sum * (1.0f / FDIM);
    float var = sumsq * (1.0f / FDIM) - mu * mu;
    float r = rsqrtf(var + LN_EPS);
    out[g * FDIM + t] = (y - mu) * r * ln_g[t] + ln_b[t];
}

// ---------------- launch ----------------

extern "C" void kernel_launch(void* const* d_in, const int* in_sizes, int n_in,
                              void* d_out, int out_size, void* d_ws, size_t ws_size,
                              hipStream_t stream) {
    const float* x_in  = (const float*)d_in[0];
    const int*   eidx  = (const int*)d_in[1];
    const int*   batch = (const int*)d_in[2];
    const float* W1 = (const float*)d_in[3];
    const float* b1 = (const float*)d_in[4];
    const float* W2 = (const float*)d_in[5];
    const float* b2 = (const float*)d_in[6];
    const float* W3 = (const float*)d_in[7];
    const float* b3 = (const float*)d_in[8];
    const float* Wm1 = (const float*)d_in[9];
    const float* bm1 = (const float*)d_in[10];
    const float* Wm2 = (const float*)d_in[11];
    const float* bm2 = (const float*)d_in[12];
    const float* ln_g = (const float*)d_in[13];
    const float* ln_b = (const float*)d_in[14];
    float* out = (float*)d_out;

    const int N = in_sizes[0] / FDIM;   // 100000
    const int E = in_sizes[1] / 2;      // 1600000
    const int G = out_size / FDIM;      // 64

    const int* src = eidx;
    const int* dst = eidx + E;

    // workspace layout
    char* p = (char*)d_ws;
    float* B0 = (float*)p;            p += (size_t)N * FDIM * 4;
    float* B1 = (float*)p;            p += (size_t)N * FDIM * 4;
    int* csr_src = (int*)p;           p += (size_t)E * 4;
    float* csr_w = (float*)p;         p += (size_t)E * 4;
    int* row_ptr = (int*)p;           p += (size_t)(N + 1) * 4;
    int* indeg = (int*)p;             p += (size_t)N * 4;
    int* cursor = (int*)p;            p += (size_t)N * 4;
    int* partials = (int*)p;          p += 1024 * 4;
    float* dinv = (float*)p;          p += (size_t)N * 4;
    float* gsums = (float*)p;         p += (size_t)G * FDIM * 4;

    const int TPB = 256;
    dim3 blk(TPB);
    dim3 gN((N + TPB - 1) / TPB);
    dim3 gE((E + TPB - 1) / TPB);
    dim3 gN32(((size_t)N * 32 + TPB - 1) / TPB);
    dim3 gGemm(N / 32);
    const int NB = (N + SCAN_TPB - 1) / SCAN_TPB;

    // ---- CSR build ----
    hipMemsetAsync(indeg, 0, (size_t)N * 4, stream);
    hipMemsetAsync(cursor, 0, (size_t)N * 4, stream);
    hipMemsetAsync(gsums, 0, (size_t)G * FDIM * 4, stream);
    k_count<<<gE, blk, 0, stream>>>(dst, indeg, E);
    k_dinv<<<gN, blk, 0, stream>>>(indeg, dinv, N);
    k_scan_chunk<<<dim3(NB), dim3(SCAN_TPB), 0, stream>>>(indeg, row_ptr, partials, N);
    k_scan_partials<<<dim3(1), dim3(1024), 0, stream>>>(partials, NB);
    k_scan_add<<<dim3(NB), dim3(SCAN_TPB), 0, stream>>>(row_ptr, partials, N);
    k_fill_csr<<<gE, blk, 0, stream>>>(src, dst, dinv, row_ptr, cursor, csr_src, csr_w, E);

    // ---- layer 1: x_in -> B1 ----
    k_gemm<<<gGemm, blk, 0, stream>>>(x_in, W1, B0);
    k_aggregate<<<gN32, blk, 0, stream>>>(B0, row_ptr, csr_src, csr_w, dinv, b1, B1, N, 1);

    // ---- layer 2 ----
    k_gemm<<<gGemm, blk, 0, stream>>>(B1, W2, B0);
    k_aggregate<<<gN32, blk, 0, stream>>>(B0, row_ptr, csr_src, csr_w, dinv, b2, B1, N, 1);

    // ---- layer 3 (no relu) ----
    k_gemm<<<gGemm, blk, 0, stream>>>(B1, W3, B0);
    k_aggregate<<<gN32, blk, 0, stream>>>(B0, row_ptr, csr_src, csr_w, dinv, b3, B1, N, 0);

    // ---- two-stage pool + MLP + LN ----
    k_pool<<<dim3((N + POOL_NODES - 1) / POOL_NODES), dim3(FDIM), 0, stream>>>(B1, batch, gsums, N);
    k_final<<<dim3(G), dim3(FDIM), 0, stream>>>(gsums, batch, N, Wm1, bm1, Wm2, bm2,
                                                ln_g, ln_b, out);
}

// Round 4
// 709.578 us; speedup vs baseline: 12.6402x; 1.2913x over previous
//
#include <hip/hip_runtime.h>

#define FDIM 128
#define LN_EPS 1e-5f
#define SCAN_TPB 256

typedef short bf16x8 __attribute__((ext_vector_type(8)));
typedef float f32x4 __attribute__((ext_vector_type(4)));

static __device__ __forceinline__ ushort f2bf(float f) {
    union { float f; unsigned u; } v; v.f = f;
    unsigned r = v.u + 0x7FFFu + ((v.u >> 16) & 1u);  // RNE
    return (ushort)(r >> 16);
}
static __device__ __forceinline__ float bf2f(ushort h) {
    union { unsigned u; float f; } v; v.u = ((unsigned)h) << 16;
    return v.f;
}

// ---------------- degree / norm precompute ----------------

__global__ void k_count(const int* __restrict__ dst, int* __restrict__ indeg, int E) {
    int e = blockIdx.x * blockDim.x + threadIdx.x;
    if (e < E) atomicAdd(&indeg[dst[e]], 1);
}

__global__ void k_dinv(const int* __restrict__ indeg, float* __restrict__ dinv, int N) {
    int i = blockIdx.x * blockDim.x + threadIdx.x;
    if (i < N) dinv[i] = rsqrtf((float)(indeg[i] + 1));  // +1 self-loop
}

// ---------------- prefix scan ----------------

__global__ void k_scan_chunk(const int* __restrict__ in, int* __restrict__ row_ptr,
                             int* __restrict__ partials, int N) {
    __shared__ int wsum[16];
    const int t = threadIdx.x;
    const int i = blockIdx.x * SCAN_TPB + t;
    int v = (i < N) ? in[i] : 0;
    const int lane = t & 63;
    const int wv = t >> 6;
    int x = v;
#pragma unroll
    for (int off = 1; off < 64; off <<= 1) {
        int y = __shfl_up(x, off, 64);
        if (lane >= off) x += y;
    }
    if (lane == 63) wsum[wv] = x;
    __syncthreads();
    if (t == 0) {
        int s = 0;
        for (int w = 0; w < SCAN_TPB / 64; w++) { int tmp = wsum[w]; wsum[w] = s; s += tmp; }
        partials[blockIdx.x] = s;
    }
    __syncthreads();
    x += wsum[wv];
    if (i < N) row_ptr[i + 1] = x;
    if (i == 0) row_ptr[0] = 0;
}

__global__ void k_scan_partials(int* __restrict__ partials, int NB) {
    __shared__ int wsum[16];
    const int t = threadIdx.x;
    int v = (t < NB) ? partials[t] : 0;
    const int lane = t & 63;
    const int wv = t >> 6;
    int x = v;
#pragma unroll
    for (int off = 1; off < 64; off <<= 1) {
        int y = __shfl_up(x, off, 64);
        if (lane >= off) x += y;
    }
    if (lane == 63) wsum[wv] = x;
    __syncthreads();
    if (t == 0) {
        int s = 0;
        for (int w = 0; w < 16; w++) { int tmp = wsum[w]; wsum[w] = s; s += tmp; }
    }
    __syncthreads();
    x += wsum[wv];
    if (t < NB) partials[t] = x - v;
}

__global__ void k_scan_add(int* __restrict__ row_ptr, const int* __restrict__ partials, int N) {
    int i = blockIdx.x * SCAN_TPB + threadIdx.x;
    if (i < N) row_ptr[i + 1] += partials[blockIdx.x];
}

// ---------------- CSR fill ----------------

__global__ void k_fill_csr(const int* __restrict__ src, const int* __restrict__ dst,
                           const float* __restrict__ dinv, const int* __restrict__ row_ptr,
                           int* __restrict__ cursor, int* __restrict__ csr_src,
                           float* __restrict__ csr_w, int E) {
    int e = blockIdx.x * blockDim.x + threadIdx.x;
    if (e >= E) return;
    int s = src[e], d = dst[e];
    int pos = atomicAdd(&cursor[d], 1);
    int slot = row_ptr[d] + pos;
    csr_src[slot] = s;
    csr_w[slot] = dinv[s] * dinv[d];
}

// ---------------- W prep: Wt[n][k] = bf16(W[k][n]) ----------------

__global__ void k_prep_w(const float* __restrict__ W, ushort* __restrict__ Wt) {
    int idx = blockIdx.x * 256 + threadIdx.x;  // 16384 total
    int nn = idx >> 7, kk = idx & 127;
    Wt[idx] = f2bf(W[kk * 128 + nn]);
}

// ---------------- MFMA GEMM: C[N,128](bf16) = X[N,128] @ W ----------------
// 128 rows/block, 4 waves; wave w covers rows 32w..32w+31 as two 16-row tiles.
// A-frag: A[m=lane&15][k=quad*8+j]; B-frag from Wt[n][k]; C/D: col=lane&15, row=quad*4+reg.

template<bool F32IN>
__launch_bounds__(256)
__global__ void k_gemm(const void* __restrict__ Xv, const ushort* __restrict__ Wt,
                       ushort* __restrict__ C, int N) {
    __shared__ ushort As[128][136];  // +8 pad -> 2-way-max bank aliasing
    __shared__ ushort Ws[128][136];
    const int t = threadIdx.x;
    const int row0 = blockIdx.x * 128;

    // stage Wt (16384 ushorts = 2048 x 16B chunks)
#pragma unroll
    for (int i = 0; i < 8; i++) {
        int c = t + i * 256;
        int r = c >> 4, c8 = (c & 15) * 8;
        *(bf16x8*)&Ws[r][c8] = *(const bf16x8*)&Wt[r * 128 + c8];
    }
    // stage A (convert on the fly for layer 1)
    if (F32IN) {
        const float* X = (const float*)Xv;
#pragma unroll
        for (int i = 0; i < 8; i++) {
            int c = t + i * 256;
            int r = c >> 4, c8 = (c & 15) * 8;
            int row = row0 + r;
            bf16x8 pk = {0, 0, 0, 0, 0, 0, 0, 0};
            if (row < N) {
                const float* sp = X + (size_t)row * FDIM + c8;
                float4 u0 = *(const float4*)(sp);
                float4 u1 = *(const float4*)(sp + 4);
                pk[0] = (short)f2bf(u0.x); pk[1] = (short)f2bf(u0.y);
                pk[2] = (short)f2bf(u0.z); pk[3] = (short)f2bf(u0.w);
                pk[4] = (short)f2bf(u1.x); pk[5] = (short)f2bf(u1.y);
                pk[6] = (short)f2bf(u1.z); pk[7] = (short)f2bf(u1.w);
            }
            *(bf16x8*)&As[r][c8] = pk;
        }
    } else {
        const ushort* X = (const ushort*)Xv;
#pragma unroll
        for (int i = 0; i < 8; i++) {
            int c = t + i * 256;
            int r = c >> 4, c8 = (c & 15) * 8;
            int row = row0 + r;
            bf16x8 pk = {0, 0, 0, 0, 0, 0, 0, 0};
            if (row < N) pk = *(const bf16x8*)&X[(size_t)row * FDIM + c8];
            *(bf16x8*)&As[r][c8] = pk;
        }
    }
    __syncthreads();

    const int w = t >> 6, l = t & 63;
    const int m = l & 15, q = l >> 4;
    const int r0 = w * 32;

    bf16x8 a0[4], a1[4];
#pragma unroll
    for (int ks = 0; ks < 4; ks++) {
        a0[ks] = *(const bf16x8*)&As[r0 + m][ks * 32 + q * 8];
        a1[ks] = *(const bf16x8*)&As[r0 + 16 + m][ks * 32 + q * 8];
    }

    f32x4 acc0[8], acc1[8];
#pragma unroll
    for (int ct = 0; ct < 8; ct++) { acc0[ct] = {0, 0, 0, 0}; acc1[ct] = {0, 0, 0, 0}; }

#pragma unroll
    for (int ct = 0; ct < 8; ct++) {
#pragma unroll
        for (int ks = 0; ks < 4; ks++) {
            bf16x8 b = *(const bf16x8*)&Ws[ct * 16 + m][ks * 32 + q * 8];
            acc0[ct] = __builtin_amdgcn_mfma_f32_16x16x32_bf16(a0[ks], b, acc0[ct], 0, 0, 0);
            acc1[ct] = __builtin_amdgcn_mfma_f32_16x16x32_bf16(a1[ks], b, acc1[ct], 0, 0, 0);
        }
    }

#pragma unroll
    for (int ct = 0; ct < 8; ct++) {
#pragma unroll
        for (int r = 0; r < 4; r++) {
            int row = row0 + r0 + q * 4 + r;
            if (row < N) C[(size_t)row * FDIM + ct * 16 + m] = f2bf(acc0[ct][r]);
            int row2 = row + 16;
            if (row2 < N) C[(size_t)row2 * FDIM + ct * 16 + m] = f2bf(acc1[ct][r]);
        }
    }
}

// ---------------- fused pull-aggregate (bf16 in/out, fp32 accumulate) ----------------
// 32 lanes/node, 4 bf16 (8B) per lane.

__launch_bounds__(256)
__global__ void k_aggregate(const ushort* __restrict__ xw, const int* __restrict__ row_ptr,
                            const int* __restrict__ csr_src, const float* __restrict__ csr_w,
                            const float* __restrict__ dinv, const float* __restrict__ bias,
                            ushort* __restrict__ out, int N, int do_relu) {
    int tid = blockIdx.x * blockDim.x + threadIdx.x;
    int n = tid >> 5;
    if (n >= N) return;
    int lane = tid & 31;

    float d = dinv[n];
    float c = d * d;
    ushort4 sv = ((const ushort4*)xw)[(size_t)n * 32 + lane];
    float ax = c * bf2f(sv.x), ay = c * bf2f(sv.y);
    float az = c * bf2f(sv.z), aw = c * bf2f(sv.w);

    const int beg = row_ptr[n], end = row_ptr[n + 1];
    for (int e = beg; e < end; e++) {
        int s = csr_src[e];
        float we = csr_w[e];
        ushort4 v = ((const ushort4*)xw)[(size_t)s * 32 + lane];
        ax += we * bf2f(v.x); ay += we * bf2f(v.y);
        az += we * bf2f(v.z); aw += we * bf2f(v.w);
    }

    const float4 bb = ((const float4*)bias)[lane];
    ax += bb.x; ay += bb.y; az += bb.z; aw += bb.w;
    if (do_relu) {
        ax = fmaxf(ax, 0.f); ay = fmaxf(ay, 0.f);
        az = fmaxf(az, 0.f); aw = fmaxf(aw, 0.f);
    }
    ushort4 o;
    o.x = f2bf(ax); o.y = f2bf(ay); o.z = f2bf(az); o.w = f2bf(aw);
    ((ushort4*)out)[(size_t)n * 32 + lane] = o;
}

// ---------------- two-stage pool ----------------

#define POOL_NODES 128

__launch_bounds__(128)
__global__ void k_pool(const ushort* __restrict__ x3, const int* __restrict__ batch,
                       float* __restrict__ sums, int N) {
    const int t = threadIdx.x;
    const int n0 = blockIdx.x * POOL_NODES;
    if (n0 >= N) return;
    const int n1 = (n0 + POOL_NODES < N) ? n0 + POOL_NODES : N;

    float acc = 0.f;
    int cur = batch[n0];
    for (int n = n0; n < n1; n++) {
        int g = batch[n];
        if (g != cur) {
            atomicAdd(&sums[cur * FDIM + t], acc);
            acc = 0.f;
            cur = g;
        }
        acc += bf2f(x3[(size_t)n * FDIM + t]);
    }
    atomicAdd(&sums[cur * FDIM + t], acc);
}

// ---------------- per-graph mean + MLP + LayerNorm ----------------

__launch_bounds__(128)
__global__ void k_final(const float* __restrict__ sums, const int* __restrict__ batch, int N,
                        const float* __restrict__ Wm1, const float* __restrict__ bm1,
                        const float* __restrict__ Wm2, const float* __restrict__ bm2,
                        const float* __restrict__ ln_g, const float* __restrict__ ln_b,
                        float* __restrict__ out) {
    const int g = blockIdx.x;
    const int t = threadIdx.x;

    int lo = 0, hi = N;
    while (lo < hi) { int mid = (lo + hi) >> 1; if (batch[mid] < g) lo = mid + 1; else hi = mid; }
    int lo2 = lo, hi2 = N;
    while (lo2 < hi2) { int mid = (lo2 + hi2) >> 1; if (batch[mid] < g + 1) lo2 = mid + 1; else hi2 = mid; }
    float cnt = (float)(lo2 - lo);

    float gl = sums[g * FDIM + t] / fmaxf(cnt, 1.0f);

    __shared__ float gbuf[FDIM];
    __shared__ float hbuf[FDIM];
    __shared__ float wsum[4];
    gbuf[t] = gl;
    __syncthreads();

    float h = bm1[t];
#pragma unroll 8
    for (int k = 0; k < FDIM; k++) h += gbuf[k] * Wm1[k * FDIM + t];
    h = fmaxf(h, 0.f);
    hbuf[t] = h;
    __syncthreads();

    float y = bm2[t];
#pragma unroll 8
    for (int k = 0; k < FDIM; k++) y += hbuf[k] * Wm2[k * FDIM + t];

    float s = y, s2 = y * y;
#pragma unroll
    for (int off = 32; off > 0; off >>= 1) {
        s += __shfl_down(s, off, 64);
        s2 += __shfl_down(s2, off, 64);
    }
    if ((t & 63) == 0) { wsum[t >> 6] = s; wsum[2 + (t >> 6)] = s2; }
    __syncthreads();
    float sum = wsum[0] + wsum[1];
    float sumsq = wsum[2] + wsum[3];
    float mu = sum * (1.0f / FDIM);
    float var = sumsq * (1.0f / FDIM) - mu * mu;
    float r = rsqrtf(var + LN_EPS);
    out[g * FDIM + t] = (y - mu) * r * ln_g[t] + ln_b[t];
}

// ---------------- launch ----------------

extern "C" void kernel_launch(void* const* d_in, const int* in_sizes, int n_in,
                              void* d_out, int out_size, void* d_ws, size_t ws_size,
                              hipStream_t stream) {
    const float* x_in  = (const float*)d_in[0];
    const int*   eidx  = (const int*)d_in[1];
    const int*   batch = (const int*)d_in[2];
    const float* W1 = (const float*)d_in[3];
    const float* b1 = (const float*)d_in[4];
    const float* W2 = (const float*)d_in[5];
    const float* b2 = (const float*)d_in[6];
    const float* W3 = (const float*)d_in[7];
    const float* b3 = (const float*)d_in[8];
    const float* Wm1 = (const float*)d_in[9];
    const float* bm1 = (const float*)d_in[10];
    const float* Wm2 = (const float*)d_in[11];
    const float* bm2 = (const float*)d_in[12];
    const float* ln_g = (const float*)d_in[13];
    const float* ln_b = (const float*)d_in[14];
    float* out = (float*)d_out;

    const int N = in_sizes[0] / FDIM;   // 100000
    const int E = in_sizes[1] / 2;      // 1600000
    const int G = out_size / FDIM;      // 64

    const int* src = eidx;
    const int* dst = eidx + E;

    // workspace layout (all offsets 16B-aligned)
    char* p = (char*)d_ws;
    ushort* B0h = (ushort*)p;         p += (size_t)N * FDIM * 2;     // 25.6 MB
    ushort* B1h = (ushort*)p;         p += (size_t)N * FDIM * 2;     // 25.6 MB
    int* csr_src = (int*)p;           p += (size_t)E * 4;
    float* csr_w = (float*)p;         p += (size_t)E * 4;
    int* row_ptr = (int*)p;           p += (size_t)(N + 4) * 4;
    int* indeg = (int*)p;             p += (size_t)N * 4;
    int* cursor = (int*)p;            p += (size_t)N * 4;
    int* partials = (int*)p;          p += 1024 * 4;
    float* dinv = (float*)p;          p += (size_t)N * 4;
    float* gsums = (float*)p;         p += (size_t)G * FDIM * 4;
    ushort* Wt1 = (ushort*)p;         p += 16384 * 2;
    ushort* Wt2 = (ushort*)p;         p += 16384 * 2;
    ushort* Wt3 = (ushort*)p;         p += 16384 * 2;

    const int TPB = 256;
    dim3 blk(TPB);
    dim3 gN((N + TPB - 1) / TPB);
    dim3 gE((E + TPB - 1) / TPB);
    dim3 gN32(((size_t)N * 32 + TPB - 1) / TPB);
    dim3 gGemm((N + 127) / 128);
    const int NB = (N + SCAN_TPB - 1) / SCAN_TPB;

    // ---- CSR build + weight prep ----
    hipMemsetAsync(indeg, 0, (size_t)N * 4, stream);
    hipMemsetAsync(cursor, 0, (size_t)N * 4, stream);
    hipMemsetAsync(gsums, 0, (size_t)G * FDIM * 4, stream);
    k_count<<<gE, blk, 0, stream>>>(dst, indeg, E);
    k_dinv<<<gN, blk, 0, stream>>>(indeg, dinv, N);
    k_scan_chunk<<<dim3(NB), dim3(SCAN_TPB), 0, stream>>>(indeg, row_ptr, partials, N);
    k_scan_partials<<<dim3(1), dim3(1024), 0, stream>>>(partials, NB);
    k_scan_add<<<dim3(NB), dim3(SCAN_TPB), 0, stream>>>(row_ptr, partials, N);
    k_fill_csr<<<gE, blk, 0, stream>>>(src, dst, dinv, row_ptr, cursor, csr_src, csr_w, E);
    k_prep_w<<<dim3(64), blk, 0, stream>>>(W1, Wt1);
    k_prep_w<<<dim3(64), blk, 0, stream>>>(W2, Wt2);
    k_prep_w<<<dim3(64), blk, 0, stream>>>(W3, Wt3);

    // ---- layer 1 (fp32 input, converts in staging) ----
    k_gemm<true><<<gGemm, blk, 0, stream>>>(x_in, Wt1, B0h, N);
    k_aggregate<<<gN32, blk, 0, stream>>>(B0h, row_ptr, csr_src, csr_w, dinv, b1, B1h, N, 1);

    // ---- layer 2 ----
    k_gemm<false><<<gGemm, blk, 0, stream>>>(B1h, Wt2, B0h, N);
    k_aggregate<<<gN32, blk, 0, stream>>>(B0h, row_ptr, csr_src, csr_w, dinv, b2, B1h, N, 1);

    // ---- layer 3 (no relu) ----
    k_gemm<false><<<gGemm, blk, 0, stream>>>(B1h, Wt3, B0h, N);
    k_aggregate<<<gN32, blk, 0, stream>>>(B0h, row_ptr, csr_src, csr_w, dinv, b3, B1h, N, 0);

    // ---- pool + MLP + LN ----
    k_pool<<<dim3((N + POOL_NODES - 1) / POOL_NODES), dim3(FDIM), 0, stream>>>(B1h, batch, gsums, N);
    k_final<<<dim3(G), dim3(FDIM), 0, stream>>>(gsums, batch, N, Wm1, bm1, Wm2, bm2,
                                                ln_g, ln_b, out);
}

// Round 5
// 648.554 us; speedup vs baseline: 13.8295x; 1.0941x over previous
//
#include <hip/hip_runtime.h>

#define FDIM 128
#define LN_EPS 1e-5f
#define SCAN_TPB 256

typedef short bf16x8 __attribute__((ext_vector_type(8)));
typedef float f32x4 __attribute__((ext_vector_type(4)));

static __device__ __forceinline__ ushort f2bf(float f) {
    union { float f; unsigned u; } v; v.f = f;
    unsigned r = v.u + 0x7FFFu + ((v.u >> 16) & 1u);  // RNE
    return (ushort)(r >> 16);
}
static __device__ __forceinline__ float bf2f(ushort h) {
    union { unsigned u; float f; } v; v.u = ((unsigned)h) << 16;
    return v.f;
}

// ---------------- degree count ----------------

__global__ void k_count(const int* __restrict__ dst, int* __restrict__ indeg, int E) {
    int e = blockIdx.x * blockDim.x + threadIdx.x;
    if (e < E) atomicAdd(&indeg[dst[e]], 1);
}

// ---------------- prefix scan (+ fused dinv) ----------------

__global__ void k_scan_chunk(const int* __restrict__ in, int* __restrict__ row_ptr,
                             int* __restrict__ partials, float* __restrict__ dinv, int N) {
    __shared__ int wsum[16];
    const int t = threadIdx.x;
    const int i = blockIdx.x * SCAN_TPB + t;
    int v = (i < N) ? in[i] : 0;
    if (i < N) dinv[i] = rsqrtf((float)(v + 1));  // +1 self-loop
    const int lane = t & 63;
    const int wv = t >> 6;
    int x = v;
#pragma unroll
    for (int off = 1; off < 64; off <<= 1) {
        int y = __shfl_up(x, off, 64);
        if (lane >= off) x += y;
    }
    if (lane == 63) wsum[wv] = x;
    __syncthreads();
    if (t == 0) {
        int s = 0;
        for (int w = 0; w < SCAN_TPB / 64; w++) { int tmp = wsum[w]; wsum[w] = s; s += tmp; }
        partials[blockIdx.x] = s;
    }
    __syncthreads();
    x += wsum[wv];
    if (i < N) row_ptr[i + 1] = x;
    if (i == 0) row_ptr[0] = 0;
}

__global__ void k_scan_partials(int* __restrict__ partials, int NB) {
    __shared__ int wsum[16];
    const int t = threadIdx.x;
    int v = (t < NB) ? partials[t] : 0;
    const int lane = t & 63;
    const int wv = t >> 6;
    int x = v;
#pragma unroll
    for (int off = 1; off < 64; off <<= 1) {
        int y = __shfl_up(x, off, 64);
        if (lane >= off) x += y;
    }
    if (lane == 63) wsum[wv] = x;
    __syncthreads();
    if (t == 0) {
        int s = 0;
        for (int w = 0; w < 16; w++) { int tmp = wsum[w]; wsum[w] = s; s += tmp; }
    }
    __syncthreads();
    x += wsum[wv];
    if (t < NB) partials[t] = x - v;
}

__global__ void k_scan_add(int* __restrict__ row_ptr, const int* __restrict__ partials, int N) {
    int i = blockIdx.x * SCAN_TPB + threadIdx.x;
    if (i < N) row_ptr[i + 1] += partials[blockIdx.x];
}

// ---------------- CSR fill (cursor-free: consumes indeg) ----------------

__global__ void k_fill_csr(const int* __restrict__ src, const int* __restrict__ dst,
                           const int* __restrict__ row_ptr, int* __restrict__ indeg,
                           int* __restrict__ csr_src, int E) {
    int e = blockIdx.x * blockDim.x + threadIdx.x;
    if (e >= E) return;
    int s = src[e], d = dst[e];
    int pos = atomicSub(&indeg[d], 1) - 1;
    csr_src[row_ptr[d] + pos] = s;
}

// ---------------- W prep: Wt[l][n][k] = bf16(W_l[k][n]), 3 layers in one ----------------

__global__ void k_prep_w(const float* __restrict__ Wa, const float* __restrict__ Wb,
                         const float* __restrict__ Wc, ushort* __restrict__ Wt) {
    int idx = blockIdx.x * 256 + threadIdx.x;  // 3*16384
    int layer = idx >> 14;
    int r = idx & 16383;
    int nn = r >> 7, kk = r & 127;
    const float* W = (layer == 0) ? Wa : (layer == 1) ? Wb : Wc;
    Wt[idx] = f2bf(W[kk * 128 + nn]);
}

// ---------------- MFMA GEMM: xs[N,128](bf16) = dinv .* (X[N,128] @ W) ----------------
// 128 rows/block, 4 waves; wave w covers rows 32w..32w+31 as two 16-row tiles.
// A-frag: A[m=lane&15][k=quad*8+j]; C/D: col=lane&15, row=quad*4+reg.

template<bool F32IN>
__launch_bounds__(256)
__global__ void k_gemm(const void* __restrict__ Xv, const ushort* __restrict__ Wt,
                       const float* __restrict__ dinv, ushort* __restrict__ C, int N) {
    __shared__ ushort As[128][136];
    __shared__ ushort Ws[128][136];
    const int t = threadIdx.x;
    const int row0 = blockIdx.x * 128;

#pragma unroll
    for (int i = 0; i < 8; i++) {
        int c = t + i * 256;
        int r = c >> 4, c8 = (c & 15) * 8;
        *(bf16x8*)&Ws[r][c8] = *(const bf16x8*)&Wt[r * 128 + c8];
    }
    if (F32IN) {
        const float* X = (const float*)Xv;
#pragma unroll
        for (int i = 0; i < 8; i++) {
            int c = t + i * 256;
            int r = c >> 4, c8 = (c & 15) * 8;
            int row = row0 + r;
            bf16x8 pk = {0, 0, 0, 0, 0, 0, 0, 0};
            if (row < N) {
                const float* sp = X + (size_t)row * FDIM + c8;
                float4 u0 = *(const float4*)(sp);
                float4 u1 = *(const float4*)(sp + 4);
                pk[0] = (short)f2bf(u0.x); pk[1] = (short)f2bf(u0.y);
                pk[2] = (short)f2bf(u0.z); pk[3] = (short)f2bf(u0.w);
                pk[4] = (short)f2bf(u1.x); pk[5] = (short)f2bf(u1.y);
                pk[6] = (short)f2bf(u1.z); pk[7] = (short)f2bf(u1.w);
            }
            *(bf16x8*)&As[r][c8] = pk;
        }
    } else {
        const ushort* X = (const ushort*)Xv;
#pragma unroll
        for (int i = 0; i < 8; i++) {
            int c = t + i * 256;
            int r = c >> 4, c8 = (c & 15) * 8;
            int row = row0 + r;
            bf16x8 pk = {0, 0, 0, 0, 0, 0, 0, 0};
            if (row < N) pk = *(const bf16x8*)&X[(size_t)row * FDIM + c8];
            *(bf16x8*)&As[r][c8] = pk;
        }
    }
    __syncthreads();

    const int w = t >> 6, l = t & 63;
    const int m = l & 15, q = l >> 4;
    const int r0 = w * 32;

    bf16x8 a0[4], a1[4];
#pragma unroll
    for (int ks = 0; ks < 4; ks++) {
        a0[ks] = *(const bf16x8*)&As[r0 + m][ks * 32 + q * 8];
        a1[ks] = *(const bf16x8*)&As[r0 + 16 + m][ks * 32 + q * 8];
    }

    f32x4 acc0[8], acc1[8];
#pragma unroll
    for (int ct = 0; ct < 8; ct++) { acc0[ct] = {0, 0, 0, 0}; acc1[ct] = {0, 0, 0, 0}; }

#pragma unroll
    for (int ct = 0; ct < 8; ct++) {
#pragma unroll
        for (int ks = 0; ks < 4; ks++) {
            bf16x8 b = *(const bf16x8*)&Ws[ct * 16 + m][ks * 32 + q * 8];
            acc0[ct] = __builtin_amdgcn_mfma_f32_16x16x32_bf16(a0[ks], b, acc0[ct], 0, 0, 0);
            acc1[ct] = __builtin_amdgcn_mfma_f32_16x16x32_bf16(a1[ks], b, acc1[ct], 0, 0, 0);
        }
    }

    // epilogue: scale row r by dinv[r], write bf16
    float dv0[4], dv1[4];
#pragma unroll
    for (int r = 0; r < 4; r++) {
        int row = row0 + r0 + q * 4 + r;
        dv0[r] = (row < N) ? dinv[row] : 0.f;
        dv1[r] = (row + 16 < N) ? dinv[row + 16] : 0.f;
    }
#pragma unroll
    for (int ct = 0; ct < 8; ct++) {
#pragma unroll
        for (int r = 0; r < 4; r++) {
            int row = row0 + r0 + q * 4 + r;
            if (row < N) C[(size_t)row * FDIM + ct * 16 + m] = f2bf(acc0[ct][r] * dv0[r]);
            int row2 = row + 16;
            if (row2 < N) C[(size_t)row2 * FDIM + ct * 16 + m] = f2bf(acc1[ct][r] * dv1[r]);
        }
    }
}

// ---------------- fused pull-aggregate ----------------
// out[n] = act(dinv[n]*(xs[n] + sum_e xs[csr_src[e]]) + b); 32 lanes/node.

__launch_bounds__(256)
__global__ void k_aggregate(const ushort* __restrict__ xs, const int* __restrict__ row_ptr,
                            const int* __restrict__ csr_src, const float* __restrict__ dinv,
                            const float* __restrict__ bias, ushort* __restrict__ out,
                            int N, int do_relu) {
    int tid = blockIdx.x * blockDim.x + threadIdx.x;
    int n = tid >> 5;
    if (n >= N) return;
    int lane = tid & 31;

    ushort4 sv = ((const ushort4*)xs)[(size_t)n * 32 + lane];
    float ax = bf2f(sv.x), ay = bf2f(sv.y), az = bf2f(sv.z), aw = bf2f(sv.w);

    const int beg = row_ptr[n];
    const int deg = row_ptr[n + 1] - beg;

    for (int base = 0; base < deg; base += 32) {
        int rem = deg - base;
        int m = (rem < 32) ? rem : 32;
        int myidx = 0;
        if (lane < m) myidx = csr_src[beg + base + lane];  // coalesced
#pragma unroll 4
        for (int j = 0; j < m; j++) {
            int s = __shfl(myidx, j, 32);
            ushort4 v = ((const ushort4*)xs)[(size_t)s * 32 + lane];
            ax += bf2f(v.x); ay += bf2f(v.y); az += bf2f(v.z); aw += bf2f(v.w);
        }
    }

    const float d = dinv[n];
    const float4 bb = ((const float4*)bias)[lane];
    ax = d * ax + bb.x; ay = d * ay + bb.y;
    az = d * az + bb.z; aw = d * aw + bb.w;
    if (do_relu) {
        ax = fmaxf(ax, 0.f); ay = fmaxf(ay, 0.f);
        az = fmaxf(az, 0.f); aw = fmaxf(aw, 0.f);
    }
    ushort4 o;
    o.x = f2bf(ax); o.y = f2bf(ay); o.z = f2bf(az); o.w = f2bf(aw);
    ((ushort4*)out)[(size_t)n * 32 + lane] = o;
}

// ---------------- two-stage pool ----------------

#define POOL_NODES 128

__launch_bounds__(128)
__global__ void k_pool(const ushort* __restrict__ x3, const int* __restrict__ batch,
                       float* __restrict__ sums, int N) {
    const int t = threadIdx.x;
    const int n0 = blockIdx.x * POOL_NODES;
    if (n0 >= N) return;
    const int n1 = (n0 + POOL_NODES < N) ? n0 + POOL_NODES : N;

    float acc = 0.f;
    int cur = batch[n0];
    for (int n = n0; n < n1; n++) {
        int g = batch[n];
        if (g != cur) {
            atomicAdd(&sums[cur * FDIM + t], acc);
            acc = 0.f;
            cur = g;
        }
        acc += bf2f(x3[(size_t)n * FDIM + t]);
    }
    atomicAdd(&sums[cur * FDIM + t], acc);
}

// ---------------- per-graph mean + MLP + LayerNorm ----------------

__launch_bounds__(128)
__global__ void k_final(const float* __restrict__ sums, const int* __restrict__ batch, int N,
                        const float* __restrict__ Wm1, const float* __restrict__ bm1,
                        const float* __restrict__ Wm2, const float* __restrict__ bm2,
                        const float* __restrict__ ln_g, const float* __restrict__ ln_b,
                        float* __restrict__ out) {
    const int g = blockIdx.x;
    const int t = threadIdx.x;

    int lo = 0, hi = N;
    while (lo < hi) { int mid = (lo + hi) >> 1; if (batch[mid] < g) lo = mid + 1; else hi = mid; }
    int lo2 = lo, hi2 = N;
    while (lo2 < hi2) { int mid = (lo2 + hi2) >> 1; if (batch[mid] < g + 1) lo2 = mid + 1; else hi2 = mid; }
    float cnt = (float)(lo2 - lo);

    float gl = sums[g * FDIM + t] / fmaxf(cnt, 1.0f);

    __shared__ float gbuf[FDIM];
    __shared__ float hbuf[FDIM];
    __shared__ float wsum[4];
    gbuf[t] = gl;
    __syncthreads();

    float h = bm1[t];
#pragma unroll 8
    for (int k = 0; k < FDIM; k++) h += gbuf[k] * Wm1[k * FDIM + t];
    h = fmaxf(h, 0.f);
    hbuf[t] = h;
    __syncthreads();

    float y = bm2[t];
#pragma unroll 8
    for (int k = 0; k < FDIM; k++) y += hbuf[k] * Wm2[k * FDIM + t];

    float s = y, s2 = y * y;
#pragma unroll
    for (int off = 32; off > 0; off >>= 1) {
        s += __shfl_down(s, off, 64);
        s2 += __shfl_down(s2, off, 64);
    }
    if ((t & 63) == 0) { wsum[t >> 6] = s; wsum[2 + (t >> 6)] = s2; }
    __syncthreads();
    float sum = wsum[0] + wsum[1];
    float sumsq = wsum[2] + wsum[3];
    float mu = sum * (1.0f / FDIM);
    float var = sumsq * (1.0f / FDIM) - mu * mu;
    float r = rsqrtf(var + LN_EPS);
    out[g * FDIM + t] = (y - mu) * r * ln_g[t] + ln_b[t];
}

// ---------------- launch ----------------

extern "C" void kernel_launch(void* const* d_in, const int* in_sizes, int n_in,
                              void* d_out, int out_size, void* d_ws, size_t ws_size,
                              hipStream_t stream) {
    const float* x_in  = (const float*)d_in[0];
    const int*   eidx  = (const int*)d_in[1];
    const int*   batch = (const int*)d_in[2];
    const float* W1 = (const float*)d_in[3];
    const float* b1 = (const float*)d_in[4];
    const float* W2 = (const float*)d_in[5];
    const float* b2 = (const float*)d_in[6];
    const float* W3 = (const float*)d_in[7];
    const float* b3 = (const float*)d_in[8];
    const float* Wm1 = (const float*)d_in[9];
    const float* bm1 = (const float*)d_in[10];
    const float* Wm2 = (const float*)d_in[11];
    const float* bm2 = (const float*)d_in[12];
    const float* ln_g = (const float*)d_in[13];
    const float* ln_b = (const float*)d_in[14];
    float* out = (float*)d_out;

    const int N = in_sizes[0] / FDIM;   // 100000
    const int E = in_sizes[1] / 2;      // 1600000
    const int G = out_size / FDIM;      // 64

    const int* src = eidx;
    const int* dst = eidx + E;

    // workspace layout
    char* p = (char*)d_ws;
    ushort* B0h = (ushort*)p;         p += (size_t)N * FDIM * 2;
    ushort* B1h = (ushort*)p;         p += (size_t)N * FDIM * 2;
    int* csr_src = (int*)p;           p += (size_t)E * 4;
    int* row_ptr = (int*)p;           p += (size_t)(N + 4) * 4;
    int* indeg = (int*)p;             p += (size_t)N * 4;
    int* partials = (int*)p;          p += 1024 * 4;
    float* dinv = (float*)p;          p += (size_t)N * 4;
    float* gsums = (float*)p;         p += (size_t)G * FDIM * 4;
    ushort* Wt = (ushort*)p;          p += 3 * 16384 * 2;

    const int TPB = 256;
    dim3 blk(TPB);
    dim3 gE((E + TPB - 1) / TPB);
    dim3 gN32(((size_t)N * 32 + TPB - 1) / TPB);
    dim3 gGemm((N + 127) / 128);
    const int NB = (N + SCAN_TPB - 1) / SCAN_TPB;

    // ---- CSR build + weight prep ----
    hipMemsetAsync(indeg, 0, (size_t)N * 4, stream);
    hipMemsetAsync(gsums, 0, (size_t)G * FDIM * 4, stream);
    k_count<<<gE, blk, 0, stream>>>(dst, indeg, E);
    k_scan_chunk<<<dim3(NB), dim3(SCAN_TPB), 0, stream>>>(indeg, row_ptr, partials, dinv, N);
    k_scan_partials<<<dim3(1), dim3(1024), 0, stream>>>(partials, NB);
    k_scan_add<<<dim3(NB), dim3(SCAN_TPB), 0, stream>>>(row_ptr, partials, N);
    k_fill_csr<<<gE, blk, 0, stream>>>(src, dst, row_ptr, indeg, csr_src, E);
    k_prep_w<<<dim3(192), blk, 0, stream>>>(W1, W2, W3, Wt);

    // ---- layer 1 (fp32 input) ----
    k_gemm<true><<<gGemm, blk, 0, stream>>>(x_in, Wt, dinv, B0h, N);
    k_aggregate<<<gN32, blk, 0, stream>>>(B0h, row_ptr, csr_src, dinv, b1, B1h, N, 1);

    // ---- layer 2 ----
    k_gemm<false><<<gGemm, blk, 0, stream>>>(B1h, Wt + 16384, dinv, B0h, N);
    k_aggregate<<<gN32, blk, 0, stream>>>(B0h, row_ptr, csr_src, dinv, b2, B1h, N, 1);

    // ---- layer 3 (no relu) ----
    k_gemm<false><<<gGemm, blk, 0, stream>>>(B1h, Wt + 32768, dinv, B0h, N);
    k_aggregate<<<gN32, blk, 0, stream>>>(B0h, row_ptr, csr_src, dinv, b3, B1h, N, 0);

    // ---- pool + MLP + LN ----
    k_pool<<<dim3((N + POOL_NODES - 1) / POOL_NODES), dim3(FDIM), 0, stream>>>(B1h, batch, gsums, N);
    k_final<<<dim3(G), dim3(FDIM), 0, stream>>>(gsums, batch, N, Wm1, bm1, Wm2, bm2,
                                                ln_g, ln_b, out);
}

// Round 6
// 569.561 us; speedup vs baseline: 15.7476x; 1.1387x over previous
//
#include <hip/hip_runtime.h>

#define FDIM 128
#define LN_EPS 1e-5f
#define SCAN_TPB 256
#define NBKT_SHIFT 10          // 1024 nodes per bucket
#define BKT_NODES 1024
#define MAXBKT 128             // supports N <= 131072

typedef short bf16x8 __attribute__((ext_vector_type(8)));
typedef float f32x4 __attribute__((ext_vector_type(4)));
typedef unsigned long long u64;

static __device__ __forceinline__ ushort f2bf(float f) {
    union { float f; unsigned u; } v; v.f = f;
    unsigned r = v.u + 0x7FFFu + ((v.u >> 16) & 1u);  // RNE
    return (ushort)(r >> 16);
}
static __device__ __forceinline__ float bf2f(ushort h) {
    union { unsigned u; float f; } v; v.u = ((unsigned)h) << 16;
    return v.f;
}

// ---------------- bucketed CSR build ----------------
// Pass A0: bucket histogram (LDS-staged, 98 global atomics per block)

__launch_bounds__(256)
__global__ void k_bkt_hist(const int* __restrict__ dst, int* __restrict__ ghist,
                           int E, int nbkt) {
    __shared__ int h[MAXBKT];
    const int t = threadIdx.x;
    for (int i = t; i < nbkt; i += 256) h[i] = 0;
    __syncthreads();
    const int E4 = E >> 2;
    const int4* d4p = (const int4*)dst;
#pragma unroll
    for (int r = 0; r < 2; r++) {
        int i4 = blockIdx.x * 512 + r * 256 + t;
        if (i4 < E4) {
            int4 d = d4p[i4];
            atomicAdd(&h[d.x >> NBKT_SHIFT], 1);
            atomicAdd(&h[d.y >> NBKT_SHIFT], 1);
            atomicAdd(&h[d.z >> NBKT_SHIFT], 1);
            atomicAdd(&h[d.w >> NBKT_SHIFT], 1);
        }
    }
    __syncthreads();
    for (int i = t; i < nbkt; i += 256) if (h[i]) atomicAdd(&ghist[i], h[i]);
}

// Pass A1: tiny scan over nbkt bucket counts -> bases + running cursors

__global__ void k_bkt_scan(const int* __restrict__ ghist, int* __restrict__ bbase,
                           int* __restrict__ bcur, int nbkt) {
    if (threadIdx.x == 0) {
        int s = 0;
        for (int b = 0; b < nbkt; b++) { bbase[b] = s; bcur[b] = s; s += ghist[b]; }
        bbase[nbkt] = s;
    }
}

// Pass A2: multisplit scatter of (src,dst) pairs into bucket-major order.
// Each block reserves one contiguous run per bucket -> near-coalesced writes.

__launch_bounds__(256)
__global__ void k_bkt_scatter(const int* __restrict__ src, const int* __restrict__ dst,
                              int* __restrict__ bcur, u64* __restrict__ bktA,
                              int E, int nbkt) {
    __shared__ int h[MAXBKT], lbase[MAXBKT], lcur[MAXBKT];
    const int t = threadIdx.x;
    for (int i = t; i < nbkt; i += 256) h[i] = 0;
    __syncthreads();
    const int E4 = E >> 2;
    const int4* s4p = (const int4*)src;
    const int4* d4p = (const int4*)dst;
    int4 sv[2], dv[2]; bool ok[2];
#pragma unroll
    for (int r = 0; r < 2; r++) {
        int i4 = blockIdx.x * 512 + r * 256 + t;
        ok[r] = (i4 < E4);
        if (ok[r]) {
            sv[r] = s4p[i4]; dv[r] = d4p[i4];
            atomicAdd(&h[dv[r].x >> NBKT_SHIFT], 1);
            atomicAdd(&h[dv[r].y >> NBKT_SHIFT], 1);
            atomicAdd(&h[dv[r].z >> NBKT_SHIFT], 1);
            atomicAdd(&h[dv[r].w >> NBKT_SHIFT], 1);
        }
    }
    __syncthreads();
    for (int i = t; i < nbkt; i += 256) {
        lbase[i] = h[i] ? atomicAdd(&bcur[i], h[i]) : 0;
        lcur[i] = 0;
    }
    __syncthreads();
#pragma unroll
    for (int r = 0; r < 2; r++) {
        if (!ok[r]) continue;
        int ss[4] = {sv[r].x, sv[r].y, sv[r].z, sv[r].w};
        int dd[4] = {dv[r].x, dv[r].y, dv[r].z, dv[r].w};
#pragma unroll
        for (int j = 0; j < 4; j++) {
            int b = dd[j] >> NBKT_SHIFT;
            int p = atomicAdd(&lcur[b], 1);
            bktA[(size_t)lbase[b] + p] = ((u64)(unsigned)ss[j] << 32) | (unsigned)dd[j];
        }
    }
}

// Pass B1: per-bucket degree count in LDS (no global per-node atomics) + dinv

__launch_bounds__(512)
__global__ void k_deg(const u64* __restrict__ bktA, const int* __restrict__ bbase,
                      int* __restrict__ deg, float* __restrict__ dinv, int N) {
    __shared__ int cnt[BKT_NODES];
    const int t = threadIdx.x;
    const int b = blockIdx.x;
    const int nb = b << NBKT_SHIFT;
    const int lim = min(BKT_NODES, N - nb);
    for (int l = t; l < BKT_NODES; l += 512) cnt[l] = 0;
    __syncthreads();
    const int beg = bbase[b], end = bbase[b + 1];
    for (int i = beg + t; i < end; i += 512) {
        int d = (int)(unsigned)bktA[i];
        atomicAdd(&cnt[d - nb], 1);
    }
    __syncthreads();
    for (int l = t; l < lim; l += 512) {
        int c = cnt[l];
        deg[nb + l] = c;
        dinv[nb + l] = rsqrtf((float)(c + 1));  // +1 self-loop
    }
}

// Pass B3: per-bucket CSR fill; each block owns a contiguous csr region.

__launch_bounds__(512)
__global__ void k_fill(const u64* __restrict__ bktA, const int* __restrict__ bbase,
                       const int* __restrict__ row_ptr, int* __restrict__ csr_src, int N) {
    __shared__ int rp[BKT_NODES];
    __shared__ int lcur[BKT_NODES];
    const int t = threadIdx.x;
    const int b = blockIdx.x;
    const int nb = b << NBKT_SHIFT;
    const int lim = min(BKT_NODES, N - nb);
    for (int l = t; l < lim; l += 512) { rp[l] = row_ptr[nb + l]; lcur[l] = 0; }
    __syncthreads();
    const int beg = bbase[b], end = bbase[b + 1];
    for (int i = beg + t; i < end; i += 512) {
        u64 pr = bktA[i];
        int d = (int)(unsigned)pr - nb;
        int s = (int)(pr >> 32);
        int p = atomicAdd(&lcur[d], 1);
        csr_src[rp[d] + p] = s;
    }
}

// ---------------- prefix scan over deg -> row_ptr ----------------

__global__ void k_scan_chunk(const int* __restrict__ in, int* __restrict__ row_ptr,
                             int* __restrict__ partials, int N) {
    __shared__ int wsum[16];
    const int t = threadIdx.x;
    const int i = blockIdx.x * SCAN_TPB + t;
    int v = (i < N) ? in[i] : 0;
    const int lane = t & 63;
    const int wv = t >> 6;
    int x = v;
#pragma unroll
    for (int off = 1; off < 64; off <<= 1) {
        int y = __shfl_up(x, off, 64);
        if (lane >= off) x += y;
    }
    if (lane == 63) wsum[wv] = x;
    __syncthreads();
    if (t == 0) {
        int s = 0;
        for (int w = 0; w < SCAN_TPB / 64; w++) { int tmp = wsum[w]; wsum[w] = s; s += tmp; }
        partials[blockIdx.x] = s;
    }
    __syncthreads();
    x += wsum[wv];
    if (i < N) row_ptr[i + 1] = x;
    if (i == 0) row_ptr[0] = 0;
}

__global__ void k_scan_partials(int* __restrict__ partials, int NB) {
    __shared__ int wsum[16];
    const int t = threadIdx.x;
    int v = (t < NB) ? partials[t] : 0;
    const int lane = t & 63;
    const int wv = t >> 6;
    int x = v;
#pragma unroll
    for (int off = 1; off < 64; off <<= 1) {
        int y = __shfl_up(x, off, 64);
        if (lane >= off) x += y;
    }
    if (lane == 63) wsum[wv] = x;
    __syncthreads();
    if (t == 0) {
        int s = 0;
        for (int w = 0; w < 16; w++) { int tmp = wsum[w]; wsum[w] = s; s += tmp; }
    }
    __syncthreads();
    x += wsum[wv];
    if (t < NB) partials[t] = x - v;
}

__global__ void k_scan_add(int* __restrict__ row_ptr, const int* __restrict__ partials, int N) {
    int i = blockIdx.x * SCAN_TPB + threadIdx.x;
    if (i < N) row_ptr[i + 1] += partials[blockIdx.x];
}

// ---------------- W prep: Wt[l][n][k] = bf16(W_l[k][n]) ----------------

__global__ void k_prep_w(const float* __restrict__ Wa, const float* __restrict__ Wb,
                         const float* __restrict__ Wc, ushort* __restrict__ Wt) {
    int idx = blockIdx.x * 256 + threadIdx.x;  // 3*16384
    int layer = idx >> 14;
    int r = idx & 16383;
    int nn = r >> 7, kk = r & 127;
    const float* W = (layer == 0) ? Wa : (layer == 1) ? Wb : Wc;
    Wt[idx] = f2bf(W[kk * 128 + nn]);
}

// ---------------- MFMA GEMM: xs[N,128](bf16) = dinv .* (X[N,128] @ W) ----------------

template<bool F32IN>
__launch_bounds__(256)
__global__ void k_gemm(const void* __restrict__ Xv, const ushort* __restrict__ Wt,
                       const float* __restrict__ dinv, ushort* __restrict__ C, int N) {
    __shared__ ushort As[128][136];
    __shared__ ushort Ws[128][136];
    const int t = threadIdx.x;
    const int row0 = blockIdx.x * 128;

#pragma unroll
    for (int i = 0; i < 8; i++) {
        int c = t + i * 256;
        int r = c >> 4, c8 = (c & 15) * 8;
        *(bf16x8*)&Ws[r][c8] = *(const bf16x8*)&Wt[r * 128 + c8];
    }
    if (F32IN) {
        const float* X = (const float*)Xv;
#pragma unroll
        for (int i = 0; i < 8; i++) {
            int c = t + i * 256;
            int r = c >> 4, c8 = (c & 15) * 8;
            int row = row0 + r;
            bf16x8 pk = {0, 0, 0, 0, 0, 0, 0, 0};
            if (row < N) {
                const float* sp = X + (size_t)row * FDIM + c8;
                float4 u0 = *(const float4*)(sp);
                float4 u1 = *(const float4*)(sp + 4);
                pk[0] = (short)f2bf(u0.x); pk[1] = (short)f2bf(u0.y);
                pk[2] = (short)f2bf(u0.z); pk[3] = (short)f2bf(u0.w);
                pk[4] = (short)f2bf(u1.x); pk[5] = (short)f2bf(u1.y);
                pk[6] = (short)f2bf(u1.z); pk[7] = (short)f2bf(u1.w);
            }
            *(bf16x8*)&As[r][c8] = pk;
        }
    } else {
        const ushort* X = (const ushort*)Xv;
#pragma unroll
        for (int i = 0; i < 8; i++) {
            int c = t + i * 256;
            int r = c >> 4, c8 = (c & 15) * 8;
            int row = row0 + r;
            bf16x8 pk = {0, 0, 0, 0, 0, 0, 0, 0};
            if (row < N) pk = *(const bf16x8*)&X[(size_t)row * FDIM + c8];
            *(bf16x8*)&As[r][c8] = pk;
        }
    }
    __syncthreads();

    const int w = t >> 6, l = t & 63;
    const int m = l & 15, q = l >> 4;
    const int r0 = w * 32;

    bf16x8 a0[4], a1[4];
#pragma unroll
    for (int ks = 0; ks < 4; ks++) {
        a0[ks] = *(const bf16x8*)&As[r0 + m][ks * 32 + q * 8];
        a1[ks] = *(const bf16x8*)&As[r0 + 16 + m][ks * 32 + q * 8];
    }

    f32x4 acc0[8], acc1[8];
#pragma unroll
    for (int ct = 0; ct < 8; ct++) { acc0[ct] = {0, 0, 0, 0}; acc1[ct] = {0, 0, 0, 0}; }

#pragma unroll
    for (int ct = 0; ct < 8; ct++) {
#pragma unroll
        for (int ks = 0; ks < 4; ks++) {
            bf16x8 b = *(const bf16x8*)&Ws[ct * 16 + m][ks * 32 + q * 8];
            acc0[ct] = __builtin_amdgcn_mfma_f32_16x16x32_bf16(a0[ks], b, acc0[ct], 0, 0, 0);
            acc1[ct] = __builtin_amdgcn_mfma_f32_16x16x32_bf16(a1[ks], b, acc1[ct], 0, 0, 0);
        }
    }

    float dv0[4], dv1[4];
#pragma unroll
    for (int r = 0; r < 4; r++) {
        int row = row0 + r0 + q * 4 + r;
        dv0[r] = (row < N) ? dinv[row] : 0.f;
        dv1[r] = (row + 16 < N) ? dinv[row + 16] : 0.f;
    }
#pragma unroll
    for (int ct = 0; ct < 8; ct++) {
#pragma unroll
        for (int r = 0; r < 4; r++) {
            int row = row0 + r0 + q * 4 + r;
            if (row < N) C[(size_t)row * FDIM + ct * 16 + m] = f2bf(acc0[ct][r] * dv0[r]);
            int row2 = row + 16;
            if (row2 < N) C[(size_t)row2 * FDIM + ct * 16 + m] = f2bf(acc1[ct][r] * dv1[r]);
        }
    }
}

// ---------------- fused pull-aggregate ----------------
// out[n] = act(dinv[n]*(xs[n] + sum_e xs[csr_src[e]]) + b); 32 lanes/node.

__launch_bounds__(256)
__global__ void k_aggregate(const ushort* __restrict__ xs, const int* __restrict__ row_ptr,
                            const int* __restrict__ csr_src, const float* __restrict__ dinv,
                            const float* __restrict__ bias, ushort* __restrict__ out,
                            int N, int do_relu) {
    int tid = blockIdx.x * blockDim.x + threadIdx.x;
    int n = tid >> 5;
    if (n >= N) return;
    int lane = tid & 31;

    ushort4 sv = ((const ushort4*)xs)[(size_t)n * 32 + lane];
    float ax = bf2f(sv.x), ay = bf2f(sv.y), az = bf2f(sv.z), aw = bf2f(sv.w);

    const int beg = row_ptr[n];
    const int deg = row_ptr[n + 1] - beg;

    for (int base = 0; base < deg; base += 32) {
        int rem = deg - base;
        int m = (rem < 32) ? rem : 32;
        int myidx = 0;
        if (lane < m) myidx = csr_src[beg + base + lane];  // coalesced
#pragma unroll 4
        for (int j = 0; j < m; j++) {
            int s = __shfl(myidx, j, 32);
            ushort4 v = ((const ushort4*)xs)[(size_t)s * 32 + lane];
            ax += bf2f(v.x); ay += bf2f(v.y); az += bf2f(v.z); aw += bf2f(v.w);
        }
    }

    const float d = dinv[n];
    const float4 bb = ((const float4*)bias)[lane];
    ax = d * ax + bb.x; ay = d * ay + bb.y;
    az = d * az + bb.z; aw = d * aw + bb.w;
    if (do_relu) {
        ax = fmaxf(ax, 0.f); ay = fmaxf(ay, 0.f);
        az = fmaxf(az, 0.f); aw = fmaxf(aw, 0.f);
    }
    ushort4 o;
    o.x = f2bf(ax); o.y = f2bf(ay); o.z = f2bf(az); o.w = f2bf(aw);
    ((ushort4*)out)[(size_t)n * 32 + lane] = o;
}

// ---------------- two-stage pool ----------------

#define POOL_NODES 128

__launch_bounds__(128)
__global__ void k_pool(const ushort* __restrict__ x3, const int* __restrict__ batch,
                       float* __restrict__ sums, int N) {
    const int t = threadIdx.x;
    const int n0 = blockIdx.x * POOL_NODES;
    if (n0 >= N) return;
    const int n1 = (n0 + POOL_NODES < N) ? n0 + POOL_NODES : N;

    float acc = 0.f;
    int cur = batch[n0];
    for (int n = n0; n < n1; n++) {
        int g = batch[n];
        if (g != cur) {
            atomicAdd(&sums[cur * FDIM + t], acc);
            acc = 0.f;
            cur = g;
        }
        acc += bf2f(x3[(size_t)n * FDIM + t]);
    }
    atomicAdd(&sums[cur * FDIM + t], acc);
}

// ---------------- per-graph mean + MLP + LayerNorm ----------------

__launch_bounds__(128)
__global__ void k_final(const float* __restrict__ sums, const int* __restrict__ batch, int N,
                        const float* __restrict__ Wm1, const float* __restrict__ bm1,
                        const float* __restrict__ Wm2, const float* __restrict__ bm2,
                        const float* __restrict__ ln_g, const float* __restrict__ ln_b,
                        float* __restrict__ out) {
    const int g = blockIdx.x;
    const int t = threadIdx.x;

    int lo = 0, hi = N;
    while (lo < hi) { int mid = (lo + hi) >> 1; if (batch[mid] < g) lo = mid + 1; else hi = mid; }
    int lo2 = lo, hi2 = N;
    while (lo2 < hi2) { int mid = (lo2 + hi2) >> 1; if (batch[mid] < g + 1) lo2 = mid + 1; else hi2 = mid; }
    float cnt = (float)(lo2 - lo);

    float gl = sums[g * FDIM + t] / fmaxf(cnt, 1.0f);

    __shared__ float gbuf[FDIM];
    __shared__ float hbuf[FDIM];
    __shared__ float wsum[4];
    gbuf[t] = gl;
    __syncthreads();

    float h = bm1[t];
#pragma unroll 8
    for (int k = 0; k < FDIM; k++) h += gbuf[k] * Wm1[k * FDIM + t];
    h = fmaxf(h, 0.f);
    hbuf[t] = h;
    __syncthreads();

    float y = bm2[t];
#pragma unroll 8
    for (int k = 0; k < FDIM; k++) y += hbuf[k] * Wm2[k * FDIM + t];

    float s = y, s2 = y * y;
#pragma unroll
    for (int off = 32; off > 0; off >>= 1) {
        s += __shfl_down(s, off, 64);
        s2 += __shfl_down(s2, off, 64);
    }
    if ((t & 63) == 0) { wsum[t >> 6] = s; wsum[2 + (t >> 6)] = s2; }
    __syncthreads();
    float sum = wsum[0] + wsum[1];
    float sumsq = wsum[2] + wsum[3];
    float mu = sum * (1.0f / FDIM);
    float var = sumsq * (1.0f / FDIM) - mu * mu;
    float r = rsqrtf(var + LN_EPS);
    out[g * FDIM + t] = (y - mu) * r * ln_g[t] + ln_b[t];
}

// ---------------- launch ----------------

extern "C" void kernel_launch(void* const* d_in, const int* in_sizes, int n_in,
                              void* d_out, int out_size, void* d_ws, size_t ws_size,
                              hipStream_t stream) {
    const float* x_in  = (const float*)d_in[0];
    const int*   eidx  = (const int*)d_in[1];
    const int*   batch = (const int*)d_in[2];
    const float* W1 = (const float*)d_in[3];
    const float* b1 = (const float*)d_in[4];
    const float* W2 = (const float*)d_in[5];
    const float* b2 = (const float*)d_in[6];
    const float* W3 = (const float*)d_in[7];
    const float* b3 = (const float*)d_in[8];
    const float* Wm1 = (const float*)d_in[9];
    const float* bm1 = (const float*)d_in[10];
    const float* Wm2 = (const float*)d_in[11];
    const float* bm2 = (const float*)d_in[12];
    const float* ln_g = (const float*)d_in[13];
    const float* ln_b = (const float*)d_in[14];
    float* out = (float*)d_out;

    const int N = in_sizes[0] / FDIM;   // 100000
    const int E = in_sizes[1] / 2;      // 1600000
    const int G = out_size / FDIM;      // 64

    const int* src = eidx;
    const int* dst = eidx + E;

    // workspace layout
    char* p = (char*)d_ws;
    u64* bktA = (u64*)p;              p += (size_t)E * 8;            // 12.8 MB
    ushort* B0h = (ushort*)p;         p += (size_t)N * FDIM * 2;     // 25.6 MB
    ushort* B1h = (ushort*)p;         p += (size_t)N * FDIM * 2;     // 25.6 MB
    int* csr_src = (int*)p;           p += (size_t)E * 4;            // 6.4 MB
    int* row_ptr = (int*)p;           p += (size_t)(N + 4) * 4;
    int* deg = (int*)p;               p += (size_t)N * 4;
    int* partials = (int*)p;          p += 1024 * 4;
    float* dinv = (float*)p;          p += (size_t)N * 4;
    float* gsums = (float*)p;         p += (size_t)G * FDIM * 4;
    ushort* Wt = (ushort*)p;          p += 3 * 16384 * 2;
    int* ghist = (int*)p;             p += MAXBKT * 4;
    int* bbase = (int*)p;             p += (MAXBKT + 4) * 4;
    int* bcur = (int*)p;              p += MAXBKT * 4;

    const int TPB = 256;
    dim3 blk(TPB);
    dim3 gN32(((size_t)N * 32 + TPB - 1) / TPB);
    dim3 gGemm((N + 127) / 128);
    const int NB = (N + SCAN_TPB - 1) / SCAN_TPB;
    const int nbkt = (N + BKT_NODES - 1) >> NBKT_SHIFT;        // 98
    const int nEb = (E + 2047) / 2048;                         // 782

    // ---- bucketed CSR build ----
    hipMemsetAsync(ghist, 0, MAXBKT * 4, stream);
    hipMemsetAsync(gsums, 0, (size_t)G * FDIM * 4, stream);
    k_bkt_hist<<<dim3(nEb), blk, 0, stream>>>(dst, ghist, E, nbkt);
    k_bkt_scan<<<dim3(1), dim3(64), 0, stream>>>(ghist, bbase, bcur, nbkt);
    k_bkt_scatter<<<dim3(nEb), blk, 0, stream>>>(src, dst, bcur, bktA, E, nbkt);
    k_deg<<<dim3(nbkt), dim3(512), 0, stream>>>(bktA, bbase, deg, dinv, N);
    k_scan_chunk<<<dim3(NB), dim3(SCAN_TPB), 0, stream>>>(deg, row_ptr, partials, N);
    k_scan_partials<<<dim3(1), dim3(1024), 0, stream>>>(partials, NB);
    k_scan_add<<<dim3(NB), dim3(SCAN_TPB), 0, stream>>>(row_ptr, partials, N);
    k_fill<<<dim3(nbkt), dim3(512), 0, stream>>>(bktA, bbase, row_ptr, csr_src, N);
    k_prep_w<<<dim3(192), blk, 0, stream>>>(W1, W2, W3, Wt);

    // ---- layer 1 (fp32 input) ----
    k_gemm<true><<<gGemm, blk, 0, stream>>>(x_in, Wt, dinv, B0h, N);
    k_aggregate<<<gN32, blk, 0, stream>>>(B0h, row_ptr, csr_src, dinv, b1, B1h, N, 1);

    // ---- layer 2 ----
    k_gemm<false><<<gGemm, blk, 0, stream>>>(B1h, Wt + 16384, dinv, B0h, N);
    k_aggregate<<<gN32, blk, 0, stream>>>(B0h, row_ptr, csr_src, dinv, b2, B1h, N, 1);

    // ---- layer 3 (no relu) ----
    k_gemm<false><<<gGemm, blk, 0, stream>>>(B1h, Wt + 32768, dinv, B0h, N);
    k_aggregate<<<gN32, blk, 0, stream>>>(B0h, row_ptr, csr_src, dinv, b3, B1h, N, 0);

    // ---- pool + MLP + LN ----
    k_pool<<<dim3((N + POOL_NODES - 1) / POOL_NODES), dim3(FDIM), 0, stream>>>(B1h, batch, gsums, N);
    k_final<<<dim3(G), dim3(FDIM), 0, stream>>>(gsums, batch, N, Wm1, bm1, Wm2, bm2,
                                                ln_g, ln_b, out);
}

// Round 7
// 540.702 us; speedup vs baseline: 16.5881x; 1.0534x over previous
//
#include <hip/hip_runtime.h>

#define FDIM 128
#define LN_EPS 1e-5f
#define SCAN_TPB 256
#define NBKT_SHIFT 10          // 1024 nodes per bucket
#define BKT_NODES 1024
#define MAXBKT 128             // supports N <= 131072

typedef short bf16x8 __attribute__((ext_vector_type(8)));
typedef float f32x4 __attribute__((ext_vector_type(4)));
typedef ushort u16x8 __attribute__((ext_vector_type(8)));
typedef unsigned long long u64;

static __device__ __forceinline__ ushort f2bf(float f) {
    union { float f; unsigned u; } v; v.f = f;
    unsigned r = v.u + 0x7FFFu + ((v.u >> 16) & 1u);  // RNE
    return (ushort)(r >> 16);
}
static __device__ __forceinline__ float bf2f(ushort h) {
    union { unsigned u; float f; } v; v.u = ((unsigned)h) << 16;
    return v.f;
}

// ---------------- bucketed CSR build ----------------

__launch_bounds__(256)
__global__ void k_bkt_hist(const int* __restrict__ dst, int* __restrict__ ghist,
                           int E, int nbkt) {
    __shared__ int h[MAXBKT];
    const int t = threadIdx.x;
    for (int i = t; i < nbkt; i += 256) h[i] = 0;
    __syncthreads();
    const int E4 = E >> 2;
    const int4* d4p = (const int4*)dst;
#pragma unroll
    for (int r = 0; r < 2; r++) {
        int i4 = blockIdx.x * 512 + r * 256 + t;
        if (i4 < E4) {
            int4 d = d4p[i4];
            atomicAdd(&h[d.x >> NBKT_SHIFT], 1);
            atomicAdd(&h[d.y >> NBKT_SHIFT], 1);
            atomicAdd(&h[d.z >> NBKT_SHIFT], 1);
            atomicAdd(&h[d.w >> NBKT_SHIFT], 1);
        }
    }
    __syncthreads();
    for (int i = t; i < nbkt; i += 256) if (h[i]) atomicAdd(&ghist[i], h[i]);
}

__global__ void k_bkt_scan(const int* __restrict__ ghist, int* __restrict__ bbase,
                           int* __restrict__ bcur, int nbkt) {
    if (threadIdx.x == 0) {
        int s = 0;
        for (int b = 0; b < nbkt; b++) { bbase[b] = s; bcur[b] = s; s += ghist[b]; }
        bbase[nbkt] = s;
    }
}

__launch_bounds__(256)
__global__ void k_bkt_scatter(const int* __restrict__ src, const int* __restrict__ dst,
                              int* __restrict__ bcur, u64* __restrict__ bktA,
                              int E, int nbkt) {
    __shared__ int h[MAXBKT], lbase[MAXBKT], lcur[MAXBKT];
    const int t = threadIdx.x;
    for (int i = t; i < nbkt; i += 256) h[i] = 0;
    __syncthreads();
    const int E4 = E >> 2;
    const int4* s4p = (const int4*)src;
    const int4* d4p = (const int4*)dst;
    int4 sv[2], dv[2]; bool ok[2];
#pragma unroll
    for (int r = 0; r < 2; r++) {
        int i4 = blockIdx.x * 512 + r * 256 + t;
        ok[r] = (i4 < E4);
        if (ok[r]) {
            sv[r] = s4p[i4]; dv[r] = d4p[i4];
            atomicAdd(&h[dv[r].x >> NBKT_SHIFT], 1);
            atomicAdd(&h[dv[r].y >> NBKT_SHIFT], 1);
            atomicAdd(&h[dv[r].z >> NBKT_SHIFT], 1);
            atomicAdd(&h[dv[r].w >> NBKT_SHIFT], 1);
        }
    }
    __syncthreads();
    for (int i = t; i < nbkt; i += 256) {
        lbase[i] = h[i] ? atomicAdd(&bcur[i], h[i]) : 0;
        lcur[i] = 0;
    }
    __syncthreads();
#pragma unroll
    for (int r = 0; r < 2; r++) {
        if (!ok[r]) continue;
        int ss[4] = {sv[r].x, sv[r].y, sv[r].z, sv[r].w};
        int dd[4] = {dv[r].x, dv[r].y, dv[r].z, dv[r].w};
#pragma unroll
        for (int j = 0; j < 4; j++) {
            int b = dd[j] >> NBKT_SHIFT;
            int p = atomicAdd(&lcur[b], 1);
            bktA[(size_t)lbase[b] + p] = ((u64)(unsigned)ss[j] << 32) | (unsigned)dd[j];
        }
    }
}

__launch_bounds__(512)
__global__ void k_deg(const u64* __restrict__ bktA, const int* __restrict__ bbase,
                      int* __restrict__ deg, float* __restrict__ dinv, int N) {
    __shared__ int cnt[BKT_NODES];
    const int t = threadIdx.x;
    const int b = blockIdx.x;
    const int nb = b << NBKT_SHIFT;
    const int lim = min(BKT_NODES, N - nb);
    for (int l = t; l < BKT_NODES; l += 512) cnt[l] = 0;
    __syncthreads();
    const int beg = bbase[b], end = bbase[b + 1];
    for (int i = beg + t; i < end; i += 512) {
        int d = (int)(unsigned)bktA[i];
        atomicAdd(&cnt[d - nb], 1);
    }
    __syncthreads();
    for (int l = t; l < lim; l += 512) {
        int c = cnt[l];
        deg[nb + l] = c;
        dinv[nb + l] = rsqrtf((float)(c + 1));  // +1 self-loop
    }
}

__launch_bounds__(512)
__global__ void k_fill(const u64* __restrict__ bktA, const int* __restrict__ bbase,
                       const int* __restrict__ row_ptr, int* __restrict__ csr_src, int N) {
    __shared__ int rp[BKT_NODES];
    __shared__ int lcur[BKT_NODES];
    const int t = threadIdx.x;
    const int b = blockIdx.x;
    const int nb = b << NBKT_SHIFT;
    const int lim = min(BKT_NODES, N - nb);
    for (int l = t; l < lim; l += 512) { rp[l] = row_ptr[nb + l]; lcur[l] = 0; }
    __syncthreads();
    const int beg = bbase[b], end = bbase[b + 1];
    for (int i = beg + t; i < end; i += 512) {
        u64 pr = bktA[i];
        int d = (int)(unsigned)pr - nb;
        int s = (int)(pr >> 32);
        int p = atomicAdd(&lcur[d], 1);
        csr_src[rp[d] + p] = s;
    }
}

// ---------------- prefix scan over deg -> row_ptr ----------------

__global__ void k_scan_chunk(const int* __restrict__ in, int* __restrict__ row_ptr,
                             int* __restrict__ partials, int N) {
    __shared__ int wsum[16];
    const int t = threadIdx.x;
    const int i = blockIdx.x * SCAN_TPB + t;
    int v = (i < N) ? in[i] : 0;
    const int lane = t & 63;
    const int wv = t >> 6;
    int x = v;
#pragma unroll
    for (int off = 1; off < 64; off <<= 1) {
        int y = __shfl_up(x, off, 64);
        if (lane >= off) x += y;
    }
    if (lane == 63) wsum[wv] = x;
    __syncthreads();
    if (t == 0) {
        int s = 0;
        for (int w = 0; w < SCAN_TPB / 64; w++) { int tmp = wsum[w]; wsum[w] = s; s += tmp; }
        partials[blockIdx.x] = s;
    }
    __syncthreads();
    x += wsum[wv];
    if (i < N) row_ptr[i + 1] = x;
    if (i == 0) row_ptr[0] = 0;
}

__global__ void k_scan_partials(int* __restrict__ partials, int NB) {
    __shared__ int wsum[16];
    const int t = threadIdx.x;
    int v = (t < NB) ? partials[t] : 0;
    const int lane = t & 63;
    const int wv = t >> 6;
    int x = v;
#pragma unroll
    for (int off = 1; off < 64; off <<= 1) {
        int y = __shfl_up(x, off, 64);
        if (lane >= off) x += y;
    }
    if (lane == 63) wsum[wv] = x;
    __syncthreads();
    if (t == 0) {
        int s = 0;
        for (int w = 0; w < 16; w++) { int tmp = wsum[w]; wsum[w] = s; s += tmp; }
    }
    __syncthreads();
    x += wsum[wv];
    if (t < NB) partials[t] = x - v;
}

__global__ void k_scan_add(int* __restrict__ row_ptr, const int* __restrict__ partials, int N) {
    int i = blockIdx.x * SCAN_TPB + threadIdx.x;
    if (i < N) row_ptr[i + 1] += partials[blockIdx.x];
}

// ---------------- W prep: Wt[l][n][k] = bf16(W_l[k][n]) ----------------

__global__ void k_prep_w(const float* __restrict__ Wa, const float* __restrict__ Wb,
                         const float* __restrict__ Wc, ushort* __restrict__ Wt) {
    int idx = blockIdx.x * 256 + threadIdx.x;  // 3*16384
    int layer = idx >> 14;
    int r = idx & 16383;
    int nn = r >> 7, kk = r & 127;
    const float* W = (layer == 0) ? Wa : (layer == 1) ? Wb : Wc;
    Wt[idx] = f2bf(W[kk * 128 + nn]);
}

// ---------------- MFMA GEMM: xs[N,128](bf16) = dinv .* (X[N,128] @ W) ----------------

template<bool F32IN>
__launch_bounds__(256)
__global__ void k_gemm(const void* __restrict__ Xv, const ushort* __restrict__ Wt,
                       const float* __restrict__ dinv, ushort* __restrict__ C, int N) {
    __shared__ ushort As[128][136];
    __shared__ ushort Ws[128][136];
    const int t = threadIdx.x;
    const int row0 = blockIdx.x * 128;

#pragma unroll
    for (int i = 0; i < 8; i++) {
        int c = t + i * 256;
        int r = c >> 4, c8 = (c & 15) * 8;
        *(bf16x8*)&Ws[r][c8] = *(const bf16x8*)&Wt[r * 128 + c8];
    }
    if (F32IN) {
        const float* X = (const float*)Xv;
#pragma unroll
        for (int i = 0; i < 8; i++) {
            int c = t + i * 256;
            int r = c >> 4, c8 = (c & 15) * 8;
            int row = row0 + r;
            bf16x8 pk = {0, 0, 0, 0, 0, 0, 0, 0};
            if (row < N) {
                const float* sp = X + (size_t)row * FDIM + c8;
                float4 u0 = *(const float4*)(sp);
                float4 u1 = *(const float4*)(sp + 4);
                pk[0] = (short)f2bf(u0.x); pk[1] = (short)f2bf(u0.y);
                pk[2] = (short)f2bf(u0.z); pk[3] = (short)f2bf(u0.w);
                pk[4] = (short)f2bf(u1.x); pk[5] = (short)f2bf(u1.y);
                pk[6] = (short)f2bf(u1.z); pk[7] = (short)f2bf(u1.w);
            }
            *(bf16x8*)&As[r][c8] = pk;
        }
    } else {
        const ushort* X = (const ushort*)Xv;
#pragma unroll
        for (int i = 0; i < 8; i++) {
            int c = t + i * 256;
            int r = c >> 4, c8 = (c & 15) * 8;
            int row = row0 + r;
            bf16x8 pk = {0, 0, 0, 0, 0, 0, 0, 0};
            if (row < N) pk = *(const bf16x8*)&X[(size_t)row * FDIM + c8];
            *(bf16x8*)&As[r][c8] = pk;
        }
    }
    __syncthreads();

    const int w = t >> 6, l = t & 63;
    const int m = l & 15, q = l >> 4;
    const int r0 = w * 32;

    bf16x8 a0[4], a1[4];
#pragma unroll
    for (int ks = 0; ks < 4; ks++) {
        a0[ks] = *(const bf16x8*)&As[r0 + m][ks * 32 + q * 8];
        a1[ks] = *(const bf16x8*)&As[r0 + 16 + m][ks * 32 + q * 8];
    }

    f32x4 acc0[8], acc1[8];
#pragma unroll
    for (int ct = 0; ct < 8; ct++) { acc0[ct] = {0, 0, 0, 0}; acc1[ct] = {0, 0, 0, 0}; }

#pragma unroll
    for (int ct = 0; ct < 8; ct++) {
#pragma unroll
        for (int ks = 0; ks < 4; ks++) {
            bf16x8 b = *(const bf16x8*)&Ws[ct * 16 + m][ks * 32 + q * 8];
            acc0[ct] = __builtin_amdgcn_mfma_f32_16x16x32_bf16(a0[ks], b, acc0[ct], 0, 0, 0);
            acc1[ct] = __builtin_amdgcn_mfma_f32_16x16x32_bf16(a1[ks], b, acc1[ct], 0, 0, 0);
        }
    }

    float dv0[4], dv1[4];
#pragma unroll
    for (int r = 0; r < 4; r++) {
        int row = row0 + r0 + q * 4 + r;
        dv0[r] = (row < N) ? dinv[row] : 0.f;
        dv1[r] = (row + 16 < N) ? dinv[row + 16] : 0.f;
    }
#pragma unroll
    for (int ct = 0; ct < 8; ct++) {
#pragma unroll
        for (int r = 0; r < 4; r++) {
            int row = row0 + r0 + q * 4 + r;
            if (row < N) C[(size_t)row * FDIM + ct * 16 + m] = f2bf(acc0[ct][r] * dv0[r]);
            int row2 = row + 16;
            if (row2 < N) C[(size_t)row2 * FDIM + ct * 16 + m] = f2bf(acc1[ct][r] * dv1[r]);
        }
    }
}

// ---------------- fused pull-aggregate, one node per wave64 ----------------
// 4 row-groups of 16 lanes; one load instruction fetches 4 src rows (1 KB).
// out[n] = act(dinv[n]*(xs[n] + sum_e xs[csr_src[e]]) + b)

__launch_bounds__(256)
__global__ void k_aggregate(const ushort* __restrict__ xs, const int* __restrict__ row_ptr,
                            const int* __restrict__ csr_src, const float* __restrict__ dinv,
                            const float* __restrict__ bias, ushort* __restrict__ out,
                            int N, int do_relu) {
    const int n = (blockIdx.x << 2) + (threadIdx.x >> 6);
    if (n >= N) return;
    const int l = threadIdx.x & 63;
    const int fl = l & 15;      // feature slot: features fl*8 .. fl*8+7
    const int grp = l >> 4;     // row group 0..3

    const u16x8* xsr = (const u16x8*)xs;   // row r, slot fl at xsr[r*16 + fl]

    float acc[8];
    // self term (all groups load same row -> broadcast; only group 0 adds)
    u16x8 sv = xsr[(size_t)n * 16 + fl];
    const float selfw = (grp == 0) ? 1.f : 0.f;
#pragma unroll
    for (int k = 0; k < 8; k++) acc[k] = selfw * bf2f(sv[k]);

    const int beg = row_ptr[n];
    const int deg = row_ptr[n + 1] - beg;

    for (int base = 0; base < deg; base += 64) {
        const int m = min(64, deg - base);
        int idx = 0;
        if (l < m) idx = csr_src[beg + base + l];  // coalesced
        const int jmax = m & ~3;
#pragma unroll 2
        for (int j = 0; j < jmax; j += 4) {
            int s = __shfl(idx, j + grp, 64);
            u16x8 v = xsr[(size_t)s * 16 + fl];
#pragma unroll
            for (int k = 0; k < 8; k++) acc[k] += bf2f(v[k]);
        }
        const int r = m - jmax;
        if (r) {
            int s = __shfl(idx, jmax + (grp < r ? grp : 0), 64);
            if (grp < r) {
                u16x8 v = xsr[(size_t)s * 16 + fl];
#pragma unroll
                for (int k = 0; k < 8; k++) acc[k] += bf2f(v[k]);
            }
        }
    }

    // reduce the 4 row-groups
#pragma unroll
    for (int k = 0; k < 8; k++) {
        acc[k] += __shfl_xor(acc[k], 16, 64);
        acc[k] += __shfl_xor(acc[k], 32, 64);
    }

    if (grp == 0) {
        const float d = dinv[n];
        const float4 b0 = ((const float4*)bias)[fl * 2];
        const float4 b1 = ((const float4*)bias)[fl * 2 + 1];
        const float bb[8] = {b0.x, b0.y, b0.z, b0.w, b1.x, b1.y, b1.z, b1.w};
        u16x8 o;
#pragma unroll
        for (int k = 0; k < 8; k++) {
            float v = d * acc[k] + bb[k];
            if (do_relu) v = fmaxf(v, 0.f);
            o[k] = f2bf(v);
        }
        ((u16x8*)out)[(size_t)n * 16 + fl] = o;
    }
}

// ---------------- two-stage pool ----------------

#define POOL_NODES 128

__launch_bounds__(128)
__global__ void k_pool(const ushort* __restrict__ x3, const int* __restrict__ batch,
                       float* __restrict__ sums, int N) {
    const int t = threadIdx.x;
    const int n0 = blockIdx.x * POOL_NODES;
    if (n0 >= N) return;
    const int n1 = (n0 + POOL_NODES < N) ? n0 + POOL_NODES : N;

    float acc = 0.f;
    int cur = batch[n0];
    for (int n = n0; n < n1; n++) {
        int g = batch[n];
        if (g != cur) {
            atomicAdd(&sums[cur * FDIM + t], acc);
            acc = 0.f;
            cur = g;
        }
        acc += bf2f(x3[(size_t)n * FDIM + t]);
    }
    atomicAdd(&sums[cur * FDIM + t], acc);
}

// ---------------- per-graph mean + MLP + LayerNorm ----------------

__launch_bounds__(128)
__global__ void k_final(const float* __restrict__ sums, const int* __restrict__ batch, int N,
                        const float* __restrict__ Wm1, const float* __restrict__ bm1,
                        const float* __restrict__ Wm2, const float* __restrict__ bm2,
                        const float* __restrict__ ln_g, const float* __restrict__ ln_b,
                        float* __restrict__ out) {
    const int g = blockIdx.x;
    const int t = threadIdx.x;

    int lo = 0, hi = N;
    while (lo < hi) { int mid = (lo + hi) >> 1; if (batch[mid] < g) lo = mid + 1; else hi = mid; }
    int lo2 = lo, hi2 = N;
    while (lo2 < hi2) { int mid = (lo2 + hi2) >> 1; if (batch[mid] < g + 1) lo2 = mid + 1; else hi2 = mid; }
    float cnt = (float)(lo2 - lo);

    float gl = sums[g * FDIM + t] / fmaxf(cnt, 1.0f);

    __shared__ float gbuf[FDIM];
    __shared__ float hbuf[FDIM];
    __shared__ float wsum[4];
    gbuf[t] = gl;
    __syncthreads();

    float h = bm1[t];
#pragma unroll 8
    for (int k = 0; k < FDIM; k++) h += gbuf[k] * Wm1[k * FDIM + t];
    h = fmaxf(h, 0.f);
    hbuf[t] = h;
    __syncthreads();

    float y = bm2[t];
#pragma unroll 8
    for (int k = 0; k < FDIM; k++) y += hbuf[k] * Wm2[k * FDIM + t];

    float s = y, s2 = y * y;
#pragma unroll
    for (int off = 32; off > 0; off >>= 1) {
        s += __shfl_down(s, off, 64);
        s2 += __shfl_down(s2, off, 64);
    }
    if ((t & 63) == 0) { wsum[t >> 6] = s; wsum[2 + (t >> 6)] = s2; }
    __syncthreads();
    float sum = wsum[0] + wsum[1];
    float sumsq = wsum[2] + wsum[3];
    float mu = sum * (1.0f / FDIM);
    float var = sumsq * (1.0f / FDIM) - mu * mu;
    float r = rsqrtf(var + LN_EPS);
    out[g * FDIM + t] = (y - mu) * r * ln_g[t] + ln_b[t];
}

// ---------------- launch ----------------

extern "C" void kernel_launch(void* const* d_in, const int* in_sizes, int n_in,
                              void* d_out, int out_size, void* d_ws, size_t ws_size,
                              hipStream_t stream) {
    const float* x_in  = (const float*)d_in[0];
    const int*   eidx  = (const int*)d_in[1];
    const int*   batch = (const int*)d_in[2];
    const float* W1 = (const float*)d_in[3];
    const float* b1 = (const float*)d_in[4];
    const float* W2 = (const float*)d_in[5];
    const float* b2 = (const float*)d_in[6];
    const float* W3 = (const float*)d_in[7];
    const float* b3 = (const float*)d_in[8];
    const float* Wm1 = (const float*)d_in[9];
    const float* bm1 = (const float*)d_in[10];
    const float* Wm2 = (const float*)d_in[11];
    const float* bm2 = (const float*)d_in[12];
    const float* ln_g = (const float*)d_in[13];
    const float* ln_b = (const float*)d_in[14];
    float* out = (float*)d_out;

    const int N = in_sizes[0] / FDIM;   // 100000
    const int E = in_sizes[1] / 2;      // 1600000
    const int G = out_size / FDIM;      // 64

    const int* src = eidx;
    const int* dst = eidx + E;

    // workspace layout
    char* p = (char*)d_ws;
    u64* bktA = (u64*)p;              p += (size_t)E * 8;
    ushort* B0h = (ushort*)p;         p += (size_t)N * FDIM * 2;
    ushort* B1h = (ushort*)p;         p += (size_t)N * FDIM * 2;
    int* csr_src = (int*)p;           p += (size_t)E * 4;
    int* row_ptr = (int*)p;           p += (size_t)(N + 4) * 4;
    int* deg = (int*)p;               p += (size_t)N * 4;
    int* partials = (int*)p;          p += 1024 * 4;
    float* dinv = (float*)p;          p += (size_t)N * 4;
    float* gsums = (float*)p;         p += (size_t)G * FDIM * 4;
    ushort* Wt = (ushort*)p;          p += 3 * 16384 * 2;
    int* ghist = (int*)p;             p += MAXBKT * 4;
    int* bbase = (int*)p;             p += (MAXBKT + 4) * 4;
    int* bcur = (int*)p;              p += MAXBKT * 4;

    const int TPB = 256;
    dim3 blk(TPB);
    dim3 gAgg((N + 3) / 4);
    dim3 gGemm((N + 127) / 128);
    const int NB = (N + SCAN_TPB - 1) / SCAN_TPB;
    const int nbkt = (N + BKT_NODES - 1) >> NBKT_SHIFT;
    const int nEb = (E + 2047) / 2048;

    // ---- bucketed CSR build ----
    hipMemsetAsync(ghist, 0, MAXBKT * 4, stream);
    hipMemsetAsync(gsums, 0, (size_t)G * FDIM * 4, stream);
    k_bkt_hist<<<dim3(nEb), blk, 0, stream>>>(dst, ghist, E, nbkt);
    k_bkt_scan<<<dim3(1), dim3(64), 0, stream>>>(ghist, bbase, bcur, nbkt);
    k_bkt_scatter<<<dim3(nEb), blk, 0, stream>>>(src, dst, bcur, bktA, E, nbkt);
    k_deg<<<dim3(nbkt), dim3(512), 0, stream>>>(bktA, bbase, deg, dinv, N);
    k_scan_chunk<<<dim3(NB), dim3(SCAN_TPB), 0, stream>>>(deg, row_ptr, partials, N);
    k_scan_partials<<<dim3(1), dim3(1024), 0, stream>>>(partials, NB);
    k_scan_add<<<dim3(NB), dim3(SCAN_TPB), 0, stream>>>(row_ptr, partials, N);
    k_fill<<<dim3(nbkt), dim3(512), 0, stream>>>(bktA, bbase, row_ptr, csr_src, N);
    k_prep_w<<<dim3(192), blk, 0, stream>>>(W1, W2, W3, Wt);

    // ---- layer 1 (fp32 input) ----
    k_gemm<true><<<gGemm, blk, 0, stream>>>(x_in, Wt, dinv, B0h, N);
    k_aggregate<<<gAgg, blk, 0, stream>>>(B0h, row_ptr, csr_src, dinv, b1, B1h, N, 1);

    // ---- layer 2 ----
    k_gemm<false><<<gGemm, blk, 0, stream>>>(B1h, Wt + 16384, dinv, B0h, N);
    k_aggregate<<<gAgg, blk, 0, stream>>>(B0h, row_ptr, csr_src, dinv, b2, B1h, N, 1);

    // ---- layer 3 (no relu) ----
    k_gemm<false><<<gGemm, blk, 0, stream>>>(B1h, Wt + 32768, dinv, B0h, N);
    k_aggregate<<<gAgg, blk, 0, stream>>>(B0h, row_ptr, csr_src, dinv, b3, B1h, N, 0);

    // ---- pool + MLP + LN ----
    k_pool<<<dim3((N + POOL_NODES - 1) / POOL_NODES), dim3(FDIM), 0, stream>>>(B1h, batch, gsums, N);
    k_final<<<dim3(G), dim3(FDIM), 0, stream>>>(gsums, batch, N, Wm1, bm1, Wm2, bm2,
                                                ln_g, ln_b, out);
}